// Round 2
// baseline (1255.584 us; speedup 1.0000x reference)
//
#include <hip/hip_runtime.h>
#include <hip/hip_bf16.h>

// B=4, T=4000, D=1024, H=8, DK=128, CHUNK=500, N=T/CHUNK=8
// I/O is fp32 (per reference); internal activations bf16, accumulation fp32.

typedef __attribute__((ext_vector_type(4))) float f32x4;
typedef __attribute__((ext_vector_type(8))) short s16x8;

#define DEV static __device__ __forceinline__

DEV float bfu(ushort u){ union{uint i; float f;} x; x.i=((uint)u)<<16; return x.f; }
DEV float bflo(uint w){ union{uint i; float f;} x; x.i=w<<16; return x.f; }
DEV float bfhi(uint w){ union{uint i; float f;} x; x.i=w&0xffff0000u; return x.f; }
DEV ushort f2bf(float f){ union{float f; uint u;} x; x.f=f; uint r = x.u + 0x7fffu + ((x.u>>16)&1u); return (ushort)(r>>16); }
DEV uint pack2(float lo, float hi){ return ((uint)f2bf(hi)<<16) | (uint)f2bf(lo); }
DEV void unpack8(uint4 u, float* f){
  f[0]=bflo(u.x); f[1]=bfhi(u.x); f[2]=bflo(u.y); f[3]=bfhi(u.y);
  f[4]=bflo(u.z); f[5]=bfhi(u.z); f[6]=bflo(u.w); f[7]=bfhi(u.w);
}
DEV void cstore(float* C, size_t i, float v){ C[i]=v; }
DEV void cstore(ushort* C, size_t i, float v){ C[i]=f2bf(v); }

// ---------------- fp32 -> bf16 convert (weights) ----------------
__global__ __launch_bounds__(256) void f2bf_kernel(const float* __restrict__ src,
                                                   ushort* __restrict__ dst, int n4) {
  int i = blockIdx.x*256+threadIdx.x;
  if (i >= n4) return;
  float4 v = ((const float4*)src)[i];
  uint2 w; w.x = pack2(v.x, v.y); w.y = pack2(v.z, v.w);
  ((uint2*)dst)[i] = w;
}

// ---------------- LayerNorm: fp32 in, bf16 out; one block per row of 1024 ----------------
__global__ __launch_bounds__(256) void ln_kernel(const float* __restrict__ x,
                                                 const float* __restrict__ gamma,
                                                 const float* __restrict__ beta,
                                                 ushort* __restrict__ xo) {
  int row = blockIdx.x;
  int tid = threadIdx.x;
  const float* xr = x + (size_t)row*1024;
  float4 u = ((const float4*)xr)[tid];
  float s = u.x+u.y+u.z+u.w;
  float sq = u.x*u.x+u.y*u.y+u.z*u.z+u.w*u.w;
  #pragma unroll
  for (int o=32;o;o>>=1){ s += __shfl_xor(s,o); sq += __shfl_xor(sq,o); }
  __shared__ float red[8];
  int wv=tid>>6, ln=tid&63;
  if (ln==0){ red[wv]=s; red[4+wv]=sq; }
  __syncthreads();
  s = red[0]+red[1]+red[2]+red[3];
  sq = red[4]+red[5]+red[6]+red[7];
  float mu = s*(1.0f/1024.0f);
  float var = sq*(1.0f/1024.0f)-mu*mu;
  float inv = rsqrtf(var+1e-5f);
  float4 gg = ((const float4*)gamma)[tid];
  float4 bb = ((const float4*)beta)[tid];
  float o0=(u.x-mu)*inv*gg.x+bb.x;
  float o1=(u.y-mu)*inv*gg.y+bb.y;
  float o2=(u.z-mu)*inv*gg.z+bb.z;
  float o3=(u.w-mu)*inv*gg.w+bb.w;
  uint2 w; w.x=pack2(o0,o1); w.y=pack2(o2,o3);
  ((uint2*)(xo+(size_t)row*1024))[tid]=w;
}

// ---------------- sin/cos tables: [4000][128] fp32 ----------------
__global__ __launch_bounds__(256) void sincos_kernel(float* __restrict__ sint, float* __restrict__ cost) {
  int idx = blockIdx.x*256+threadIdx.x;
  if (idx >= 4000*64) return;
  int t = idx>>6, i = idx&63;
  float ang = expf(-9.210340371976184f * (float)i * (1.0f/63.0f)); // 10000^(-i/63)
  float a = (float)t * ang;
  float sv = sinf(a), cv = cosf(a);
  sint[(size_t)t*128+2*i] = sv; sint[(size_t)t*128+2*i+1] = sv;
  cost[(size_t)t*128+2*i] = cv; cost[(size_t)t*128+2*i+1] = cv;
}

// ---------------- MFMA bf16 GEMM: C[M,N] = A[M,K] @ B[K,N] ----------------
// 128x128 tile, BK=32, 4 waves (2x2), each wave 64x64 via 4x4 16x16x32 MFMAs.
template<typename OutT>
__global__ __launch_bounds__(256) void gemm_bf16(const ushort* __restrict__ A,
                                                 const ushort* __restrict__ B,
                                                 OutT* __restrict__ C,
                                                 int M, int N, int K) {
  __shared__ ushort As[128][40];   // rows padded to 40 shorts (80B, 16B-aligned)
  __shared__ ushort Bs[128][40];   // B transposed: Bs[n][k]
  int bm = blockIdx.x*128, bn = blockIdx.y*128;
  int tid = threadIdx.x;
  int wave = tid>>6, lane = tid&63;
  int wm = (wave>>1)*64, wn = (wave&1)*64;
  int rsel = lane&15, ko = (lane>>4)*8;
  f32x4 acc[4][4];
  #pragma unroll
  for (int i=0;i<4;i++)
    #pragma unroll
    for (int j=0;j<4;j++){ acc[i][j][0]=0; acc[i][j][1]=0; acc[i][j][2]=0; acc[i][j][3]=0; }
  int arow = tid>>1, ak0=(tid&1)*16;
  int bk = tid>>3, bn0=(tid&7)*16;
  const ushort* aptr = A + (size_t)(bm+arow)*K + ak0;
  const ushort* bptr = B + (size_t)bk*N + bn + bn0;
  for (int kt=0; kt<K; kt+=32) {
    uint4 a0 = *(const uint4*)(aptr+kt);
    uint4 a1 = *(const uint4*)(aptr+kt+8);
    uint4 b0 = *(const uint4*)(bptr+(size_t)kt*N);
    uint4 b1 = *(const uint4*)(bptr+(size_t)kt*N+8);
    __syncthreads();
    *(uint4*)&As[arow][ak0]   = a0;
    *(uint4*)&As[arow][ak0+8] = a1;
    union { uint4 u4[2]; ushort s[16]; } tmp;
    tmp.u4[0] = b0; tmp.u4[1] = b1;
    #pragma unroll
    for (int j=0;j<16;j++) Bs[bn0+j][bk] = tmp.s[j];
    __syncthreads();
    s16x8 af[4], bfr[4];
    #pragma unroll
    for (int mf=0;mf<4;mf++) af[mf]  = *(const s16x8*)&As[wm+mf*16+rsel][ko];
    #pragma unroll
    for (int nf=0;nf<4;nf++) bfr[nf] = *(const s16x8*)&Bs[wn+nf*16+rsel][ko];
    #pragma unroll
    for (int mf=0;mf<4;mf++)
      #pragma unroll
      for (int nf=0;nf<4;nf++)
        acc[mf][nf] = __builtin_amdgcn_mfma_f32_16x16x32_bf16(af[mf], bfr[nf], acc[mf][nf], 0,0,0);
  }
  int crow = bm+wm+(lane>>4)*4;
  int ccol = bn+wn+(lane&15);
  #pragma unroll
  for (int mf=0;mf<4;mf++)
    #pragma unroll
    for (int nf=0;nf<4;nf++)
      #pragma unroll
      for (int r2=0;r2<4;r2++)
        cstore(C, (size_t)(crow+mf*16+r2)*N + ccol+nf*16, acc[mf][nf][r2]);
}

// ---------------- rotary (theta_shift) in-place on q and k; k gets DK^-0.5 ----------------
__global__ __launch_bounds__(256) void rotary_kernel(ushort* __restrict__ q, ushort* __restrict__ k,
                                                     const float* __restrict__ sint,
                                                     const float* __restrict__ cost) {
  int idx = blockIdx.x*256+threadIdx.x;   // over 16000*512 pairs
  if (idx >= 16000*512) return;
  int row = idx>>9, cp = idx&511;
  int col = cp*2;
  int t = row - (row/4000)*4000;
  int d = col & 127;
  float c = cost[(size_t)t*128+d], s = sint[(size_t)t*128+d];
  uint* qp = (uint*)(q + (size_t)row*1024 + col);
  uint w = *qp;
  float q0=bflo(w), q1=bfhi(w);
  *qp = pack2(q0*c - q1*s, q1*c + q0*s);
  uint* kp = (uint*)(k + (size_t)row*1024 + col);
  w = *kp;
  float k0=bflo(w), k1=bfhi(w);
  const float sc = 0.08838834764831845f;  // 128^-0.5
  *kp = pack2((k0*c - k1*s)*sc, (k1*c + k0*s)*sc);
}

// ---------------- kv[bnh][128][128] = kr^T @ (v * value_inner_decay) ----------------
__global__ __launch_bounds__(256) void kv_kernel(const ushort* __restrict__ kr,
                                                 const ushort* __restrict__ v,
                                                 float* __restrict__ kv) {
  int bnh = blockIdx.x;
  int h = bnh&7, n=(bnh>>3)&7, b=bnh>>6;
  size_t base = (size_t)(b*4000+n*500)*1024 + h*128;
  float Dh = 1.0f - exp2f(-5.0f-(float)h);
  float decay = logf(Dh);
  float ls = (1.0f - expf(decay*500.0f))/(1.0f-Dh);
  float inv_ls = 1.0f/ls;
  __shared__ ushort krt[64][128];
  __shared__ ushort vdt[64][128];
  int tid=threadIdx.x;
  int tk=tid>>4, tv=tid&15;
  int srow=tid>>2, sc0=(tid&3)*32;
  float acc[8][8];
  #pragma unroll
  for (int i=0;i<8;i++)
    #pragma unroll
    for(int j=0;j<8;j++) acc[i][j]=0;
  for (int ct=0; ct<500; ct+=64) {
    int cn = min(64, 500-ct);
    __syncthreads();
    if (srow<cn) {
      const ushort* kp = kr + base + (size_t)(ct+srow)*1024 + sc0;
      const ushort* vp = v  + base + (size_t)(ct+srow)*1024 + sc0;
      float vid = expf(decay*(float)(499-(ct+srow)))*inv_ls;
      #pragma unroll
      for (int j=0;j<4;j++) {
        *(uint4*)&krt[srow][sc0+j*8] = *(const uint4*)(kp+j*8);
        uint4 vv = *(const uint4*)(vp+j*8);
        float vf[8]; unpack8(vv,vf);
        uint4 w2;
        w2.x = pack2(vf[0]*vid, vf[1]*vid);
        w2.y = pack2(vf[2]*vid, vf[3]*vid);
        w2.z = pack2(vf[4]*vid, vf[5]*vid);
        w2.w = pack2(vf[6]*vid, vf[7]*vid);
        *(uint4*)&vdt[srow][sc0+j*8] = w2;
      }
    }
    __syncthreads();
    for (int c=0;c<cn;c++) {
      uint4 ka = *(const uint4*)&krt[c][tk*8];
      uint4 vb = *(const uint4*)&vdt[c][tv*8];
      float kf[8], vf[8];
      unpack8(ka,kf); unpack8(vb,vf);
      #pragma unroll
      for (int i=0;i<8;i++)
        #pragma unroll
        for (int j=0;j<8;j++)
          acc[i][j] += kf[i]*vf[j];
    }
  }
  float* outp = kv + (size_t)bnh*16384;
  #pragma unroll
  for (int i=0;i<8;i++)
    #pragma unroll
    for (int j=0;j<8;j++)
      outp[(size_t)(tk*8+i)*128 + tv*8+j] = acc[i][j];
}

// ---------------- sequential scan over chunks per (b,h); kvrec emitted bf16 ----------------
__global__ __launch_bounds__(256) void scan_kernel(const float* __restrict__ kv,
                                                   ushort* __restrict__ kvrec,
                                                   float* __restrict__ crosssc) {
  int bh = blockIdx.x;           // 32
  int b = bh>>3, h = bh&7;
  float Dh = 1.0f - exp2f(-5.0f-(float)h);
  float decay = logf(Dh);
  float cd = expf(decay*500.0f); // cross_decay
  int tid=threadIdx.x;
  int vcol = tid&127, khalf = tid>>7;
  float st[64];
  #pragma unroll
  for (int i=0;i<64;i++) st[i]=0;
  float scale = 1.0f;
  __shared__ float colpart[2][128];
  __shared__ float sred[2];
  for (int n=0;n<8;n++) {
    int bnh = (b*8+n)*8+h;
    const float* src = kv + (size_t)bnh*16384;
    ushort* rec = kvrec + (size_t)bnh*16384;
    float inv = 1.0f/scale;
    float cs = 0;
    #pragma unroll
    for (int i=0;i<64;i++) {
      int kk = khalf*64+i;
      rec[(size_t)kk*128+vcol] = f2bf(st[i]*inv);
      st[i] = st[i]*cd + src[(size_t)kk*128+vcol];
      cs += fabsf(st[i]);
    }
    if (tid==0) crosssc[bnh] = scale;
    colpart[khalf][vcol] = cs;
    __syncthreads();
    if (tid<128) colpart[0][tid] += colpart[1][tid];
    __syncthreads();
    float m = (tid<128)? colpart[0][tid] : 0.0f;
    #pragma unroll
    for (int o=32;o;o>>=1) m = fmaxf(m,__shfl_xor(m,o));
    if (tid<128 && (tid&63)==0) sred[tid>>6]=m;
    __syncthreads();
    scale = fmaxf(fmaxf(sred[0],sred[1]),1.0f);
    __syncthreads();
  }
}

// ---- inner qk (+|qk| row-sum for inner_scale) + inner@v + cross + combine -> O[b,t,h,dv] ----
__global__ __launch_bounds__(256) void iout_kernel(const ushort* __restrict__ qr,
                                                   const ushort* __restrict__ kr,
                                                   const ushort* __restrict__ v,
                                                   const ushort* __restrict__ kvrec,
                                                   const float* __restrict__ crosssc,
                                                   ushort* __restrict__ O) {
  int bnh = blockIdx.x, rt = blockIdx.y;
  int h = bnh&7, n=(bnh>>3)&7, b=bnh>>6;
  size_t base = (size_t)(b*4000+n*500)*1024 + h*128;
  float Dh = 1.0f - exp2f(-5.0f-(float)h);
  float decay = logf(Dh);
  __shared__ ushort sh[3*64*136];       // qt | ktl | vtl ; phase2 reuses ktl+vtl as kvr[128][136]
  ushort* qt  = sh;
  ushort* ktl = sh + 64*136;
  ushort* vtl = sh + 2*64*136;
  int tid=threadIdx.x;
  int rl=tid>>2, vg=tid&3;
  int r=rt*64+rl;
  bool active = (r<500);
  int srow=tid>>2, sc0=(tid&3)*32;
  int gq = rt*64+srow;
  if (gq<500) {
    #pragma unroll
    for (int j=0;j<4;j++)
      *(uint4*)&qt[srow*136+sc0+j*8] = *(const uint4*)(qr+base+(size_t)gq*1024+sc0+j*8);
  }
  __syncthreads();
  float qreg[32];
  if (active) {
    #pragma unroll
    for (int j=0;j<4;j++){ uint4 u=*(const uint4*)&qt[rl*136+vg*32+j*8]; unpack8(u,qreg+j*8); }
  }
  float iacc[32];
  #pragma unroll
  for (int j=0;j<32;j++) iacc[j]=0;
  float partial = 0.0f;       // sum of |qk*mask_raw| for inner_scale
  for (int et=0; et<=rt; et++) {
    int ebase=et*64, cn=min(64,500-ebase);
    __syncthreads();
    if (srow<cn) {
      #pragma unroll
      for (int j=0;j<4;j++){
        *(uint4*)&ktl[srow*136+sc0+j*8] = *(const uint4*)(kr+base+(size_t)(ebase+srow)*1024+sc0+j*8);
        *(uint4*)&vtl[srow*136+sc0+j*8] = *(const uint4*)(v +base+(size_t)(ebase+srow)*1024+sc0+j*8);
      }
    }
    __syncthreads();
    if (active) {
      int emax = min(cn, r-ebase+1);
      for (int el=0; el<emax; el++) {
        float pd=0;
        #pragma unroll
        for (int j=0;j<4;j++){
          uint4 u=*(const uint4*)&ktl[el*136+vg*32+j*8];
          float kf[8]; unpack8(u,kf);
          #pragma unroll
          for(int d2=0;d2<8;d2++) pd += qreg[j*8+d2]*kf[d2];
        }
        pd += __shfl_xor(pd,1);
        pd += __shfl_xor(pd,2);
        float w = expf(decay*(float)(r-(ebase+el)));
        float sw = pd * w;
        partial += fabsf(sw);
        #pragma unroll
        for (int j=0;j<4;j++){
          uint4 u=*(const uint4*)&vtl[el*136+vg*32+j*8];
          float vf[8]; unpack8(u,vf);
          #pragma unroll
          for(int d2=0;d2<8;d2++) iacc[j*8+d2] += sw*vf[d2];
        }
      }
    }
  }
  // phase 2: cross output via kv_rec (bf16, staged into reused ktl+vtl region)
  __syncthreads();
  {
    int kk=tid>>1, c0=(tid&1)*64;
    const ushort* src = kvrec + (size_t)bnh*16384 + (size_t)kk*128 + c0;
    ushort* kvr = ktl;
    #pragma unroll
    for (int j=0;j<8;j++) *(uint4*)&kvr[kk*136+c0+j*8] = *(const uint4*)(src+j*8);
  }
  __syncthreads();
  if (active) {
    ushort* kvr = ktl;
    float cacc[32];
    #pragma unroll
    for (int j=0;j<32;j++) cacc[j]=0;
    for (int kk=0;kk<128;kk++) {
      float qv = bfu(qt[rl*136+kk]);
      #pragma unroll
      for (int j=0;j<4;j++){
        uint4 u=*(const uint4*)&kvr[kk*136+vg*32+j*8];
        float kf[8]; unpack8(u,kf);
        #pragma unroll
        for(int d2=0;d2<8;d2++) cacc[j*8+d2] += qv*kf[d2];
      }
    }
    float rs = (1.0f-expf(decay*(float)(r+1)))/(1.0f-Dh);
    float rsr = rsqrtf(rs);
    float is = fmaxf(1.0f, partial*rsr);
    float cs = crosssc[bnh];
    float all = fmaxf(is,cs);
    float lsum = (1.0f-expf(decay*500.0f))/(1.0f-Dh);
    float qid = expf(decay*(float)(r+1))*lsum*rsr;
    float fi = rsr/all;        // inner term: iacc_raw * rsr / all
    float fc = qid*(cs/all);   // cross term: cacc * qid * cs / all
    uint wbuf[16];
    #pragma unroll
    for (int j=0;j<16;j++){
      float r0 = iacc[2*j]*fi   + cacc[2*j]*fc;
      float r1 = iacc[2*j+1]*fi + cacc[2*j+1]*fc;
      wbuf[j] = pack2(r0,r1);
    }
    ushort* dst = O + (size_t)(b*4000+n*500+r)*1024 + h*128 + vg*32;
    #pragma unroll
    for (int j=0;j<4;j++) *(uint4*)(dst+j*8) = *(uint4*)&wbuf[j*4];
  }
}

// ---------------- per-head RMS norm + silu(g) gate ----------------
__global__ __launch_bounds__(256) void rms_silu_kernel(const ushort* __restrict__ O,
                                                       const ushort* __restrict__ g,
                                                       ushort* __restrict__ op) {
  int row = blockIdx.x, tid=threadIdx.x;
  int wave=tid>>6, lane=tid&63;
  const ushort* Orow = O + (size_t)row*1024;
  const ushort* grow = g + (size_t)row*1024;
  ushort* orow = op + (size_t)row*1024;
  for (int hh=0; hh<2; hh++) {
    int h = wave*2+hh;
    int c0 = h*128+lane, c1=c0+64;
    float a = bfu(Orow[c0]), b2 = bfu(Orow[c1]);
    float ss = a*a+b2*b2;
    #pragma unroll
    for (int o=32;o;o>>=1) ss += __shfl_xor(ss,o);
    float sc = rsqrtf(ss*(1.0f/128.0f)+1e-6f);
    float g0=bfu(grow[c0]), g1=bfu(grow[c1]);
    float s0 = g0/(1.0f+expf(-g0)), s1 = g1/(1.0f+expf(-g1));
    orow[c0] = f2bf(s0*a*sc);
    orow[c1] = f2bf(s1*b2*sc);
  }
}

extern "C" void kernel_launch(void* const* d_in, const int* in_sizes, int n_in,
                              void* d_out, int out_size, void* d_ws, size_t ws_size,
                              hipStream_t stream) {
  const float* x     = (const float*)d_in[0];
  const float* gamma = (const float*)d_in[1];
  const float* beta  = (const float*)d_in[2];
  const float* Wq    = (const float*)d_in[3];
  const float* Wk    = (const float*)d_in[4];
  const float* Wv    = (const float*)d_in[5];
  const float* Wg    = (const float*)d_in[6];
  const float* Wo    = (const float*)d_in[7];
  float* out = (float*)d_out;

  char* ws = (char*)d_ws;
  size_t off = 0;
  auto alloc = [&](size_t bytes)->void* { void* p = ws+off; off += (bytes+255)&~(size_t)255; return p; };
  const size_t BT1024 = (size_t)16000*1024;
  ushort* xln  = (ushort*)alloc(BT1024*2);   // reused as opre after g-GEMM
  ushort* q    = (ushort*)alloc(BT1024*2);
  ushort* k    = (ushort*)alloc(BT1024*2);
  ushort* v    = (ushort*)alloc(BT1024*2);
  ushort* g    = (ushort*)alloc(BT1024*2);
  ushort* O    = (ushort*)alloc(BT1024*2);
  ushort* Wqb  = (ushort*)alloc((size_t)1024*1024*2);
  ushort* Wkb  = (ushort*)alloc((size_t)1024*1024*2);
  ushort* Wvb  = (ushort*)alloc((size_t)1024*1024*2);
  ushort* Wgb  = (ushort*)alloc((size_t)1024*1024*2);
  ushort* Wob  = (ushort*)alloc((size_t)1024*1024*2);
  float* sint  = (float*)alloc((size_t)4000*128*4);
  float* cost  = (float*)alloc((size_t)4000*128*4);
  float* kv    = (float*)alloc((size_t)256*16384*4);
  ushort* kvrec= (ushort*)alloc((size_t)256*16384*2);
  float* crosssc = (float*)alloc(256*4);
  (void)ws_size; (void)in_sizes; (void)n_in; (void)out_size;

  ln_kernel<<<16000,256,0,stream>>>(x,gamma,beta,xln);
  sincos_kernel<<<1000,256,0,stream>>>(sint,cost);
  const int W4 = 1024*1024/4;        // 262144 float4s per weight
  f2bf_kernel<<<W4/256,256,0,stream>>>(Wq,Wqb,W4);
  f2bf_kernel<<<W4/256,256,0,stream>>>(Wk,Wkb,W4);
  f2bf_kernel<<<W4/256,256,0,stream>>>(Wv,Wvb,W4);
  f2bf_kernel<<<W4/256,256,0,stream>>>(Wg,Wgb,W4);
  f2bf_kernel<<<W4/256,256,0,stream>>>(Wo,Wob,W4);

  dim3 gg(125,8);
  gemm_bf16<ushort><<<gg,256,0,stream>>>(xln,Wqb,q,16000,1024,1024);
  gemm_bf16<ushort><<<gg,256,0,stream>>>(xln,Wkb,k,16000,1024,1024);
  gemm_bf16<ushort><<<gg,256,0,stream>>>(xln,Wvb,v,16000,1024,1024);
  gemm_bf16<ushort><<<gg,256,0,stream>>>(xln,Wgb,g,16000,1024,1024);

  rotary_kernel<<<32000,256,0,stream>>>(q,k,sint,cost);

  kv_kernel<<<256,256,0,stream>>>(k,v,kv);
  scan_kernel<<<32,256,0,stream>>>(kv,kvrec,crosssc);

  dim3 gr(256,8);
  iout_kernel<<<gr,256,0,stream>>>(q,k,v,kvrec,crosssc,O);

  ushort* opre = xln;   // xln dead after the 4 projection GEMMs
  rms_silu_kernel<<<16000,256,0,stream>>>(O,g,opre);
  gemm_bf16<float><<<gg,256,0,stream>>>(opre,Wob,out,16000,1024,1024);
}

// Round 3
// 744.181 us; speedup vs baseline: 1.6872x; 1.6872x over previous
//
#include <hip/hip_runtime.h>
#include <hip/hip_bf16.h>

// B=4, T=4000, D=1024, H=8, DK=128, CHUNK=500, N=T/CHUNK=8
// I/O is fp32 (per reference); internal activations bf16, accumulation fp32.

typedef __attribute__((ext_vector_type(4))) float f32x4;
typedef __attribute__((ext_vector_type(8))) short s16x8;

#define DEV static __device__ __forceinline__

DEV float bfu(ushort u){ union{uint i; float f;} x; x.i=((uint)u)<<16; return x.f; }
DEV float bflo(uint w){ union{uint i; float f;} x; x.i=w<<16; return x.f; }
DEV float bfhi(uint w){ union{uint i; float f;} x; x.i=w&0xffff0000u; return x.f; }
DEV ushort f2bf(float f){ union{float f; uint u;} x; x.f=f; uint r = x.u + 0x7fffu + ((x.u>>16)&1u); return (ushort)(r>>16); }
DEV uint pack2(float lo, float hi){ return ((uint)f2bf(hi)<<16) | (uint)f2bf(lo); }
DEV void unpack8(uint4 u, float* f){
  f[0]=bflo(u.x); f[1]=bfhi(u.x); f[2]=bflo(u.y); f[3]=bfhi(u.y);
  f[4]=bflo(u.z); f[5]=bfhi(u.z); f[6]=bflo(u.w); f[7]=bfhi(u.w);
}
DEV void cstore(float* C, size_t i, float v){ C[i]=v; }
DEV void cstore(ushort* C, size_t i, float v){ C[i]=f2bf(v); }

// ---------------- fp32 -> bf16 convert (weights) ----------------
__global__ __launch_bounds__(256) void f2bf_kernel(const float* __restrict__ src,
                                                   ushort* __restrict__ dst, int n4) {
  int i = blockIdx.x*256+threadIdx.x;
  if (i >= n4) return;
  float4 v = ((const float4*)src)[i];
  uint2 w; w.x = pack2(v.x, v.y); w.y = pack2(v.z, v.w);
  ((uint2*)dst)[i] = w;
}

// ---------------- LayerNorm: fp32 in, bf16 out; one block per row of 1024 ----------------
__global__ __launch_bounds__(256) void ln_kernel(const float* __restrict__ x,
                                                 const float* __restrict__ gamma,
                                                 const float* __restrict__ beta,
                                                 ushort* __restrict__ xo) {
  int row = blockIdx.x;
  int tid = threadIdx.x;
  const float* xr = x + (size_t)row*1024;
  float4 u = ((const float4*)xr)[tid];
  float s = u.x+u.y+u.z+u.w;
  float sq = u.x*u.x+u.y*u.y+u.z*u.z+u.w*u.w;
  #pragma unroll
  for (int o=32;o;o>>=1){ s += __shfl_xor(s,o); sq += __shfl_xor(sq,o); }
  __shared__ float red[8];
  int wv=tid>>6, ln=tid&63;
  if (ln==0){ red[wv]=s; red[4+wv]=sq; }
  __syncthreads();
  s = red[0]+red[1]+red[2]+red[3];
  sq = red[4]+red[5]+red[6]+red[7];
  float mu = s*(1.0f/1024.0f);
  float var = sq*(1.0f/1024.0f)-mu*mu;
  float inv = rsqrtf(var+1e-5f);
  float4 gg = ((const float4*)gamma)[tid];
  float4 bb = ((const float4*)beta)[tid];
  float o0=(u.x-mu)*inv*gg.x+bb.x;
  float o1=(u.y-mu)*inv*gg.y+bb.y;
  float o2=(u.z-mu)*inv*gg.z+bb.z;
  float o3=(u.w-mu)*inv*gg.w+bb.w;
  uint2 w; w.x=pack2(o0,o1); w.y=pack2(o2,o3);
  ((uint2*)(xo+(size_t)row*1024))[tid]=w;
}

// ---------------- sin/cos tables: [4000][128] fp32 ----------------
__global__ __launch_bounds__(256) void sincos_kernel(float* __restrict__ sint, float* __restrict__ cost) {
  int idx = blockIdx.x*256+threadIdx.x;
  if (idx >= 4000*64) return;
  int t = idx>>6, i = idx&63;
  float ang = expf(-9.210340371976184f * (float)i * (1.0f/63.0f)); // 10000^(-i/63)
  float a = (float)t * ang;
  float sv = sinf(a), cv = cosf(a);
  sint[(size_t)t*128+2*i] = sv; sint[(size_t)t*128+2*i+1] = sv;
  cost[(size_t)t*128+2*i] = cv; cost[(size_t)t*128+2*i+1] = cv;
}

// ---------------- MFMA bf16 GEMM: C[M,N] = A[M,K] @ B[K,N] ----------------
template<typename OutT>
__global__ __launch_bounds__(256) void gemm_bf16(const ushort* __restrict__ A,
                                                 const ushort* __restrict__ B,
                                                 OutT* __restrict__ C,
                                                 int M, int N, int K) {
  __shared__ ushort As[128][40];
  __shared__ ushort Bs[128][40];   // B transposed: Bs[n][k]
  int bm = blockIdx.x*128, bn = blockIdx.y*128;
  int tid = threadIdx.x;
  int wave = tid>>6, lane = tid&63;
  int wm = (wave>>1)*64, wn = (wave&1)*64;
  int rsel = lane&15, ko = (lane>>4)*8;
  f32x4 acc[4][4];
  #pragma unroll
  for (int i=0;i<4;i++)
    #pragma unroll
    for (int j=0;j<4;j++){ acc[i][j][0]=0; acc[i][j][1]=0; acc[i][j][2]=0; acc[i][j][3]=0; }
  int arow = tid>>1, ak0=(tid&1)*16;
  int bk = tid>>3, bn0=(tid&7)*16;
  const ushort* aptr = A + (size_t)(bm+arow)*K + ak0;
  const ushort* bptr = B + (size_t)bk*N + bn + bn0;
  for (int kt=0; kt<K; kt+=32) {
    uint4 a0 = *(const uint4*)(aptr+kt);
    uint4 a1 = *(const uint4*)(aptr+kt+8);
    uint4 b0 = *(const uint4*)(bptr+(size_t)kt*N);
    uint4 b1 = *(const uint4*)(bptr+(size_t)kt*N+8);
    __syncthreads();
    *(uint4*)&As[arow][ak0]   = a0;
    *(uint4*)&As[arow][ak0+8] = a1;
    union { uint4 u4[2]; ushort s[16]; } tmp;
    tmp.u4[0] = b0; tmp.u4[1] = b1;
    #pragma unroll
    for (int j=0;j<16;j++) Bs[bn0+j][bk] = tmp.s[j];
    __syncthreads();
    s16x8 af[4], bfr[4];
    #pragma unroll
    for (int mf=0;mf<4;mf++) af[mf]  = *(const s16x8*)&As[wm+mf*16+rsel][ko];
    #pragma unroll
    for (int nf=0;nf<4;nf++) bfr[nf] = *(const s16x8*)&Bs[wn+nf*16+rsel][ko];
    #pragma unroll
    for (int mf=0;mf<4;mf++)
      #pragma unroll
      for (int nf=0;nf<4;nf++)
        acc[mf][nf] = __builtin_amdgcn_mfma_f32_16x16x32_bf16(af[mf], bfr[nf], acc[mf][nf], 0,0,0);
  }
  int crow = bm+wm+(lane>>4)*4;
  int ccol = bn+wn+(lane&15);
  #pragma unroll
  for (int mf=0;mf<4;mf++)
    #pragma unroll
    for (int nf=0;nf<4;nf++)
      #pragma unroll
      for (int r2=0;r2<4;r2++)
        cstore(C, (size_t)(crow+mf*16+r2)*N + ccol+nf*16, acc[mf][nf][r2]);
}

// ---------------- rotary (theta_shift) in-place on q and k; k gets DK^-0.5 ----------------
__global__ __launch_bounds__(256) void rotary_kernel(ushort* __restrict__ q, ushort* __restrict__ k,
                                                     const float* __restrict__ sint,
                                                     const float* __restrict__ cost) {
  int idx = blockIdx.x*256+threadIdx.x;   // over 16000*512 pairs
  if (idx >= 16000*512) return;
  int row = idx>>9, cp = idx&511;
  int col = cp*2;
  int t = row - (row/4000)*4000;
  int d = col & 127;
  float c = cost[(size_t)t*128+d], s = sint[(size_t)t*128+d];
  uint* qp = (uint*)(q + (size_t)row*1024 + col);
  uint w = *qp;
  float q0=bflo(w), q1=bfhi(w);
  *qp = pack2(q0*c - q1*s, q1*c + q0*s);
  uint* kp = (uint*)(k + (size_t)row*1024 + col);
  w = *kp;
  float k0=bflo(w), k1=bfhi(w);
  const float sc = 0.08838834764831845f;  // 128^-0.5
  *kp = pack2((k0*c - k1*s)*sc, (k1*c + k0*s)*sc);
}

// ---------------- kv[bnh][128][128] = kr^T @ (v * value_inner_decay) ----------------
__global__ __launch_bounds__(256) void kv_kernel(const ushort* __restrict__ kr,
                                                 const ushort* __restrict__ v,
                                                 float* __restrict__ kv) {
  int bnh = blockIdx.x;
  int h = bnh&7, n=(bnh>>3)&7, b=bnh>>6;
  size_t base = (size_t)(b*4000+n*500)*1024 + h*128;
  float Dh = 1.0f - exp2f(-5.0f-(float)h);
  float decay = logf(Dh);
  float ls = (1.0f - expf(decay*500.0f))/(1.0f-Dh);
  float inv_ls = 1.0f/ls;
  __shared__ ushort krt[64][128];
  __shared__ ushort vdt[64][128];
  int tid=threadIdx.x;
  int tk=tid>>4, tv=tid&15;
  int srow=tid>>2, sc0=(tid&3)*32;
  float acc[8][8];
  #pragma unroll
  for (int i=0;i<8;i++)
    #pragma unroll
    for(int j=0;j<8;j++) acc[i][j]=0;
  for (int ct=0; ct<500; ct+=64) {
    int cn = min(64, 500-ct);
    __syncthreads();
    if (srow<cn) {
      const ushort* kp = kr + base + (size_t)(ct+srow)*1024 + sc0;
      const ushort* vp = v  + base + (size_t)(ct+srow)*1024 + sc0;
      float vid = expf(decay*(float)(499-(ct+srow)))*inv_ls;
      #pragma unroll
      for (int j=0;j<4;j++) {
        *(uint4*)&krt[srow][sc0+j*8] = *(const uint4*)(kp+j*8);
        uint4 vv = *(const uint4*)(vp+j*8);
        float vf[8]; unpack8(vv,vf);
        uint4 w2;
        w2.x = pack2(vf[0]*vid, vf[1]*vid);
        w2.y = pack2(vf[2]*vid, vf[3]*vid);
        w2.z = pack2(vf[4]*vid, vf[5]*vid);
        w2.w = pack2(vf[6]*vid, vf[7]*vid);
        *(uint4*)&vdt[srow][sc0+j*8] = w2;
      }
    }
    __syncthreads();
    for (int c=0;c<cn;c++) {
      uint4 ka = *(const uint4*)&krt[c][tk*8];
      uint4 vb = *(const uint4*)&vdt[c][tv*8];
      float kf[8], vf[8];
      unpack8(ka,kf); unpack8(vb,vf);
      #pragma unroll
      for (int i=0;i<8;i++)
        #pragma unroll
        for (int j=0;j<8;j++)
          acc[i][j] += kf[i]*vf[j];
    }
  }
  float* outp = kv + (size_t)bnh*16384;
  #pragma unroll
  for (int i=0;i<8;i++)
    #pragma unroll
    for (int j=0;j<8;j++)
      outp[(size_t)(tk*8+i)*128 + tv*8+j] = acc[i][j];
}

// ------- sequential scan over chunks per (b,h); kvrec emitted bf16 TRANSPOSED [dv][k] -------
__global__ __launch_bounds__(256) void scan_kernel(const float* __restrict__ kv,
                                                   ushort* __restrict__ kvrecT,
                                                   float* __restrict__ crosssc) {
  int bh = blockIdx.x;           // 32
  int b = bh>>3, h = bh&7;
  float Dh = 1.0f - exp2f(-5.0f-(float)h);
  float decay = logf(Dh);
  float cd = expf(decay*500.0f); // cross_decay
  int tid=threadIdx.x;
  int vcol = tid&127, khalf = tid>>7;
  float st[64];
  #pragma unroll
  for (int i=0;i<64;i++) st[i]=0;
  float scale = 1.0f;
  __shared__ float colpart[2][128];
  __shared__ float sred[2];
  for (int n=0;n<8;n++) {
    int bnh = (b*8+n)*8+h;
    const float* src = kv + (size_t)bnh*16384;
    ushort* rec = kvrecT + (size_t)bnh*16384;
    float inv = 1.0f/scale;
    float cs = 0;
    #pragma unroll
    for (int i=0;i<64;i++) {
      int kk = khalf*64+i;
      rec[(size_t)vcol*128+kk] = f2bf(st[i]*inv);   // transposed: [dv][k]
      st[i] = st[i]*cd + src[(size_t)kk*128+vcol];
      cs += fabsf(st[i]);
    }
    if (tid==0) crosssc[bnh] = scale;
    colpart[khalf][vcol] = cs;
    __syncthreads();
    if (tid<128) colpart[0][tid] += colpart[1][tid];
    __syncthreads();
    float m = (tid<128)? colpart[0][tid] : 0.0f;
    #pragma unroll
    for (int o=32;o;o>>=1) m = fmaxf(m,__shfl_xor(m,o));
    if (tid<128 && (tid&63)==0) sred[tid>>6]=m;
    __syncthreads();
    scale = fmaxf(fmaxf(sred[0],sred[1]),1.0f);
    __syncthreads();
  }
}

// ---- MFMA retention: S=QK^T (masked, abs-rowsum) ; O_inner=P@V ; O_cross=Q@kvrec ; combine ----
// block = (bnh, rt): 64 q-rows, 4 waves (wave wv owns rows [16wv,16wv+16))
__global__ __launch_bounds__(256) void iout_mfma(const ushort* __restrict__ qr,
                                                 const ushort* __restrict__ kr,
                                                 const ushort* __restrict__ v,
                                                 const ushort* __restrict__ kvrecT,
                                                 const float* __restrict__ crosssc,
                                                 ushort* __restrict__ O) {
  int bnh = blockIdx.x, rt = blockIdx.y;
  int h = bnh&7, n=(bnh>>3)&7, b=bnh>>6;
  size_t base = (size_t)(b*4000+n*500)*1024 + h*128;
  float Dh = 1.0f - exp2f(-5.0f-(float)h);
  float decay = logf(Dh);

  __shared__ ushort sh[31232];       // 62464 B
  ushort* qt = sh;                   // [64][136]  Q rows
  ushort* kt = sh + 8704;            // [64][136]  K rows (e-tile)
  ushort* vt = sh + 17408;           // [128][72]  V^T (e-tile)
  ushort* pt = sh + 26624;           // [64][72]   P tile
  ushort* kvt = sh + 8704;           // phase2: [128][136] kvrec^T (reuses kt+vt)

  int tid = threadIdx.x;
  int wv = tid>>6, l = tid&63;
  int g = l>>4, c16 = l&15;
  int srow = tid>>2, sc0 = (tid&3)*32;

  // stage Q (rows clamped for the rt=7 tail)
  {
    int gq = rt*64+srow; if (gq>499) gq=499;
    const ushort* src = qr + base + (size_t)gq*1024 + sc0;
    #pragma unroll
    for (int j=0;j<4;j++) *(uint4*)&qt[srow*136 + sc0 + j*8] = *(const uint4*)(src + j*8);
  }
  int r_base = rt*64 + wv*16 + g*4;
  float er[4];
  #pragma unroll
  for (int reg=0;reg<4;reg++) er[reg] = expf(decay*(float)(r_base+reg));

  f32x4 pv[8], cc[8];
  #pragma unroll
  for (int i=0;i<8;i++){
    #pragma unroll
    for (int j=0;j<4;j++){ pv[i][j]=0.0f; cc[i][j]=0.0f; }
  }
  float rowsum[4] = {0,0,0,0};
  __syncthreads();

  for (int et=0; et<=rt; et++) {
    if (et) __syncthreads();               // protect kt/vt from previous tile's readers
    // stage K rows + V^T
    {
      int ge = et*64+srow; if (ge>499) ge=499;
      const ushort* ks = kr + base + (size_t)ge*1024 + sc0;
      const ushort* vs = v  + base + (size_t)ge*1024 + sc0;
      #pragma unroll
      for (int j=0;j<4;j++) {
        *(uint4*)&kt[srow*136 + sc0 + j*8] = *(const uint4*)(ks + j*8);
        union{uint4 u; ushort s[8];} tv; tv.u = *(const uint4*)(vs + j*8);
        #pragma unroll
        for (int x=0;x<8;x++) vt[(sc0+j*8+x)*72 + srow] = tv.s[x];
      }
    }
    __syncthreads();
    // S = Q K^T  (64x64, this wave's 16 rows)
    f32x4 S[4];
    #pragma unroll
    for (int i=0;i<4;i++){ S[i][0]=0; S[i][1]=0; S[i][2]=0; S[i][3]=0; }
    #pragma unroll
    for (int kc=0;kc<4;kc++) {
      s16x8 a = *(const s16x8*)&qt[(wv*16 + c16)*136 + kc*32 + g*8];
      #pragma unroll
      for (int ni=0;ni<4;ni++) {
        s16x8 bf2 = *(const s16x8*)&kt[(ni*16 + c16)*136 + kc*32 + g*8];
        S[ni] = __builtin_amdgcn_mfma_f32_16x16x32_bf16(a, bf2, S[ni], 0,0,0);
      }
    }
    // mask + rowsum + write P (own wave's rows only -> no barrier needed before PV)
    #pragma unroll
    for (int ni=0;ni<4;ni++) {
      int e_rel = et*64 + ni*16 + c16;
      float ie = expf(-decay*(float)e_rel);
      #pragma unroll
      for (int reg=0;reg<4;reg++) {
        int rr = r_base + reg;
        float p = (e_rel <= rr) ? S[ni][reg]*er[reg]*ie : 0.0f;
        rowsum[reg] += fabsf(p);
        pt[(wv*16 + g*4 + reg)*72 + ni*16 + c16] = f2bf(p);
      }
    }
    // O_inner += P @ V
    #pragma unroll
    for (int kc=0;kc<2;kc++) {
      s16x8 pa = *(const s16x8*)&pt[(wv*16 + c16)*72 + kc*32 + g*8];
      #pragma unroll
      for (int nf=0;nf<8;nf++) {
        s16x8 vb = *(const s16x8*)&vt[(nf*16 + c16)*72 + kc*32 + g*8];
        pv[nf] = __builtin_amdgcn_mfma_f32_16x16x32_bf16(pa, vb, pv[nf], 0,0,0);
      }
    }
  }
  // rowsum: butterfly over the 16-lane column group
  #pragma unroll
  for (int reg=0;reg<4;reg++) {
    float s = rowsum[reg];
    s += __shfl_xor(s,1); s += __shfl_xor(s,2); s += __shfl_xor(s,4); s += __shfl_xor(s,8);
    rowsum[reg] = s;
  }
  // phase 2: cross output
  __syncthreads();
  {
    int r2 = tid>>1, c0 = (tid&1)*64;
    const ushort* src = kvrecT + (size_t)bnh*16384 + (size_t)r2*128 + c0;
    #pragma unroll
    for (int j=0;j<8;j++) *(uint4*)&kvt[r2*136 + c0 + j*8] = *(const uint4*)(src + j*8);
  }
  __syncthreads();
  #pragma unroll
  for (int kc=0;kc<4;kc++) {
    s16x8 a = *(const s16x8*)&qt[(wv*16 + c16)*136 + kc*32 + g*8];
    #pragma unroll
    for (int nf=0;nf<8;nf++) {
      s16x8 bb = *(const s16x8*)&kvt[(nf*16 + c16)*136 + kc*32 + g*8];
      cc[nf] = __builtin_amdgcn_mfma_f32_16x16x32_bf16(a, bb, cc[nf], 0,0,0);
    }
  }
  // epilogue: combine + store
  float cs = crosssc[bnh];
  float lsum = (1.0f-expf(decay*500.0f))/(1.0f-Dh);
  #pragma unroll
  for (int reg=0;reg<4;reg++) {
    int rr = r_base + reg;
    if (rr < 500) {
      float rs = (1.0f-expf(decay*(float)(rr+1)))/(1.0f-Dh);
      float rsr = rsqrtf(rs);
      float is = fmaxf(1.0f, rowsum[reg]*rsr);
      float all = fmaxf(is, cs);
      float qid = expf(decay*(float)(rr+1))*lsum*rsr;
      float fi = rsr/all;
      float fc = qid*(cs/all);
      ushort* dst = O + (size_t)(b*4000+n*500+rr)*1024 + h*128;
      #pragma unroll
      for (int nf=0;nf<8;nf++)
        dst[nf*16 + c16] = f2bf(pv[nf][reg]*fi + cc[nf][reg]*fc);
    }
  }
}

// ---------------- per-head RMS norm + silu(g) gate ----------------
__global__ __launch_bounds__(256) void rms_silu_kernel(const ushort* __restrict__ O,
                                                       const ushort* __restrict__ g,
                                                       ushort* __restrict__ op) {
  int row = blockIdx.x, tid=threadIdx.x;
  int wave=tid>>6, lane=tid&63;
  const ushort* Orow = O + (size_t)row*1024;
  const ushort* grow = g + (size_t)row*1024;
  ushort* orow = op + (size_t)row*1024;
  for (int hh=0; hh<2; hh++) {
    int h = wave*2+hh;
    int c0 = h*128+lane, c1=c0+64;
    float a = bfu(Orow[c0]), b2 = bfu(Orow[c1]);
    float ss = a*a+b2*b2;
    #pragma unroll
    for (int o=32;o;o>>=1) ss += __shfl_xor(ss,o);
    float sc = rsqrtf(ss*(1.0f/128.0f)+1e-6f);
    float g0=bfu(grow[c0]), g1=bfu(grow[c1]);
    float s0 = g0/(1.0f+expf(-g0)), s1 = g1/(1.0f+expf(-g1));
    orow[c0] = f2bf(s0*a*sc);
    orow[c1] = f2bf(s1*b2*sc);
  }
}

extern "C" void kernel_launch(void* const* d_in, const int* in_sizes, int n_in,
                              void* d_out, int out_size, void* d_ws, size_t ws_size,
                              hipStream_t stream) {
  const float* x     = (const float*)d_in[0];
  const float* gamma = (const float*)d_in[1];
  const float* beta  = (const float*)d_in[2];
  const float* Wq    = (const float*)d_in[3];
  const float* Wk    = (const float*)d_in[4];
  const float* Wv    = (const float*)d_in[5];
  const float* Wg    = (const float*)d_in[6];
  const float* Wo    = (const float*)d_in[7];
  float* out = (float*)d_out;

  char* ws = (char*)d_ws;
  size_t off = 0;
  auto alloc = [&](size_t bytes)->void* { void* p = ws+off; off += (bytes+255)&~(size_t)255; return p; };
  const size_t BT1024 = (size_t)16000*1024;
  ushort* xln  = (ushort*)alloc(BT1024*2);   // reused as opre after g-GEMM
  ushort* q    = (ushort*)alloc(BT1024*2);
  ushort* k    = (ushort*)alloc(BT1024*2);
  ushort* v    = (ushort*)alloc(BT1024*2);
  ushort* g    = (ushort*)alloc(BT1024*2);
  ushort* O    = (ushort*)alloc(BT1024*2);
  ushort* Wqb  = (ushort*)alloc((size_t)1024*1024*2);
  ushort* Wkb  = (ushort*)alloc((size_t)1024*1024*2);
  ushort* Wvb  = (ushort*)alloc((size_t)1024*1024*2);
  ushort* Wgb  = (ushort*)alloc((size_t)1024*1024*2);
  ushort* Wob  = (ushort*)alloc((size_t)1024*1024*2);
  float* sint  = (float*)alloc((size_t)4000*128*4);
  float* cost  = (float*)alloc((size_t)4000*128*4);
  float* kv    = (float*)alloc((size_t)256*16384*4);
  ushort* kvrecT=(ushort*)alloc((size_t)256*16384*2);
  float* crosssc = (float*)alloc(256*4);
  (void)ws_size; (void)in_sizes; (void)n_in; (void)out_size;

  ln_kernel<<<16000,256,0,stream>>>(x,gamma,beta,xln);
  sincos_kernel<<<1000,256,0,stream>>>(sint,cost);
  const int W4 = 1024*1024/4;
  f2bf_kernel<<<W4/256,256,0,stream>>>(Wq,Wqb,W4);
  f2bf_kernel<<<W4/256,256,0,stream>>>(Wk,Wkb,W4);
  f2bf_kernel<<<W4/256,256,0,stream>>>(Wv,Wvb,W4);
  f2bf_kernel<<<W4/256,256,0,stream>>>(Wg,Wgb,W4);
  f2bf_kernel<<<W4/256,256,0,stream>>>(Wo,Wob,W4);

  dim3 gg(125,8);
  gemm_bf16<ushort><<<gg,256,0,stream>>>(xln,Wqb,q,16000,1024,1024);
  gemm_bf16<ushort><<<gg,256,0,stream>>>(xln,Wkb,k,16000,1024,1024);
  gemm_bf16<ushort><<<gg,256,0,stream>>>(xln,Wvb,v,16000,1024,1024);
  gemm_bf16<ushort><<<gg,256,0,stream>>>(xln,Wgb,g,16000,1024,1024);

  rotary_kernel<<<32000,256,0,stream>>>(q,k,sint,cost);

  kv_kernel<<<256,256,0,stream>>>(k,v,kv);
  scan_kernel<<<32,256,0,stream>>>(kv,kvrecT,crosssc);

  dim3 gr(256,8);
  iout_mfma<<<gr,256,0,stream>>>(q,k,v,kvrecT,crosssc,O);

  ushort* opre = xln;   // xln dead after the 4 projection GEMMs
  rms_silu_kernel<<<16000,256,0,stream>>>(O,g,opre);
  gemm_bf16<float><<<gg,256,0,stream>>>(opre,Wob,out,16000,1024,1024);
}

// Round 4
// 569.901 us; speedup vs baseline: 2.2032x; 1.3058x over previous
//
#include <hip/hip_runtime.h>
#include <hip/hip_bf16.h>

// B=4, T=4000, D=1024, H=8, DK=128, CHUNK=500, N=T/CHUNK=8
// I/O is fp32 (per reference); internal activations bf16, accumulation fp32.

typedef __attribute__((ext_vector_type(4))) float f32x4;
typedef __attribute__((ext_vector_type(8))) short s16x8;

#define DEV static __device__ __forceinline__

DEV float bfu(ushort u){ union{uint i; float f;} x; x.i=((uint)u)<<16; return x.f; }
DEV float bflo(uint w){ union{uint i; float f;} x; x.i=w<<16; return x.f; }
DEV float bfhi(uint w){ union{uint i; float f;} x; x.i=w&0xffff0000u; return x.f; }
DEV ushort f2bf(float f){ union{float f; uint u;} x; x.f=f; uint r = x.u + 0x7fffu + ((x.u>>16)&1u); return (ushort)(r>>16); }
DEV uint pack2(float lo, float hi){ return ((uint)f2bf(hi)<<16) | (uint)f2bf(lo); }
DEV void unpack8(uint4 u, float* f){
  f[0]=bflo(u.x); f[1]=bfhi(u.x); f[2]=bflo(u.y); f[3]=bfhi(u.y);
  f[4]=bflo(u.z); f[5]=bfhi(u.z); f[6]=bflo(u.w); f[7]=bfhi(u.w);
}
DEV void cstore(float* C, size_t i, float v){ C[i]=v; }
DEV void cstore(ushort* C, size_t i, float v){ C[i]=f2bf(v); }

// async global->LDS, 16B per lane; lds dest = wave-uniform base + lane*16
DEV void gload16(const ushort* g, ushort* l) {
  __builtin_amdgcn_global_load_lds((const __attribute__((address_space(1))) void*)g,
                                   (__attribute__((address_space(3))) void*)l, 16, 0, 0);
}

// ---------------- fp32 W[K][N] -> bf16 W^T[N][K] (64x64 tile transpose) ----------------
__global__ __launch_bounds__(256) void f2bf_t_kernel(const float* __restrict__ src,
                                                     ushort* __restrict__ dst) {
  __shared__ ushort t[64][72];
  int kt = blockIdx.x*64, nt = blockIdx.y*64;
  int tid = threadIdx.x;
  int r = tid>>2, c0 = (tid&3)*16;
  const float* s = src + (size_t)(kt+r)*1024 + nt + c0;
  #pragma unroll
  for (int j=0;j<16;j+=4) {
    float4 vv = *(const float4*)(s+j);
    t[r][c0+j]=f2bf(vv.x); t[r][c0+j+1]=f2bf(vv.y); t[r][c0+j+2]=f2bf(vv.z); t[r][c0+j+3]=f2bf(vv.w);
  }
  __syncthreads();
  union { uint4 u4[2]; ushort s16[16]; } tmp;
  #pragma unroll
  for (int j=0;j<16;j++) tmp.s16[j] = t[c0+j][r];
  ushort* d = dst + (size_t)(nt+r)*1024 + kt + c0;
  *(uint4*)(d)   = tmp.u4[0];
  *(uint4*)(d+8) = tmp.u4[1];
}

// ---------------- LayerNorm: fp32 in, bf16 out; one block per row of 1024 ----------------
__global__ __launch_bounds__(256) void ln_kernel(const float* __restrict__ x,
                                                 const float* __restrict__ gamma,
                                                 const float* __restrict__ beta,
                                                 ushort* __restrict__ xo) {
  int row = blockIdx.x;
  int tid = threadIdx.x;
  const float* xr = x + (size_t)row*1024;
  float4 u = ((const float4*)xr)[tid];
  float s = u.x+u.y+u.z+u.w;
  float sq = u.x*u.x+u.y*u.y+u.z*u.z+u.w*u.w;
  #pragma unroll
  for (int o=32;o;o>>=1){ s += __shfl_xor(s,o); sq += __shfl_xor(sq,o); }
  __shared__ float red[8];
  int wv=tid>>6, ln=tid&63;
  if (ln==0){ red[wv]=s; red[4+wv]=sq; }
  __syncthreads();
  s = red[0]+red[1]+red[2]+red[3];
  sq = red[4]+red[5]+red[6]+red[7];
  float mu = s*(1.0f/1024.0f);
  float var = sq*(1.0f/1024.0f)-mu*mu;
  float inv = rsqrtf(var+1e-5f);
  float4 gg = ((const float4*)gamma)[tid];
  float4 bb = ((const float4*)beta)[tid];
  float o0=(u.x-mu)*inv*gg.x+bb.x;
  float o1=(u.y-mu)*inv*gg.y+bb.y;
  float o2=(u.z-mu)*inv*gg.z+bb.z;
  float o3=(u.w-mu)*inv*gg.w+bb.w;
  uint2 w; w.x=pack2(o0,o1); w.y=pack2(o2,o3);
  ((uint2*)(xo+(size_t)row*1024))[tid]=w;
}

// ---------------- sin/cos tables: [4000][128] fp32 ----------------
__global__ __launch_bounds__(256) void sincos_kernel(float* __restrict__ sint, float* __restrict__ cost) {
  int idx = blockIdx.x*256+threadIdx.x;
  if (idx >= 4000*64) return;
  int t = idx>>6, i = idx&63;
  float ang = expf(-9.210340371976184f * (float)i * (1.0f/63.0f)); // 10000^(-i/63)
  float a = (float)t * ang;
  float sv = sinf(a), cv = cosf(a);
  sint[(size_t)t*128+2*i] = sv; sint[(size_t)t*128+2*i+1] = sv;
  cost[(size_t)t*128+2*i] = cv; cost[(size_t)t*128+2*i+1] = cv;
}

// ---------------- MFMA bf16 GEMM (B^T form): C[M,N] = A[M,K] @ BT[N,K]^T ----------------
// 128x128 tile, BK=32, 4 waves (2x2), global_load_lds width=16 staging (m97 structure).
template<typename OutT>
__global__ __launch_bounds__(256) void gemm_bt(const ushort* __restrict__ A,
                                               const ushort* __restrict__ BT,
                                               OutT* __restrict__ C,
                                               int M, int N, int K) {
  __shared__ ushort As[128*32];
  __shared__ ushort Bs[128*32];
  int bm = blockIdx.x*128, bn = blockIdx.y*128;
  int tid = threadIdx.x;
  int w = tid>>6, l = tid&63;
  int wm = (w>>1)*64, wn = (w&1)*64;
  int rsel = l&15, ko = (l>>4)*8;
  f32x4 acc[4][4];
  #pragma unroll
  for (int i=0;i<4;i++)
    #pragma unroll
    for (int j=0;j<4;j++){ acc[i][j][0]=0; acc[i][j][1]=0; acc[i][j][2]=0; acc[i][j][3]=0; }
  // staging addresses: wave w covers rows [w*32, w*32+32) of the 128-row tile,
  // lane l -> row w*32 + s*16 + (l>>2), k-chunk (l&3)*8 shorts (16B)
  const ushort* ap0 = A  + (size_t)(bm + w*32 + (l>>2))*K + (l&3)*8;
  const ushort* ap1 = ap0 + (size_t)16*K;
  const ushort* bp0 = BT + (size_t)(bn + w*32 + (l>>2))*K + (l&3)*8;
  const ushort* bp1 = bp0 + (size_t)16*K;
  ushort* abase = As + w*1024;        // 2048B per wave-segment (32 rows x 64B)
  ushort* bbase = Bs + w*1024;
  for (int kt=0; kt<K; kt+=32) {
    __syncthreads();                   // previous compute done reading LDS
    gload16(ap0+kt, abase);
    gload16(ap1+kt, abase+512);
    gload16(bp0+kt, bbase);
    gload16(bp1+kt, bbase+512);
    __syncthreads();                   // drains vmcnt -> tiles resident
    s16x8 af[4], bfr[4];
    #pragma unroll
    for (int mf=0;mf<4;mf++) af[mf]  = *(const s16x8*)&As[(wm+mf*16+rsel)*32 + ko];
    #pragma unroll
    for (int nf=0;nf<4;nf++) bfr[nf] = *(const s16x8*)&Bs[(wn+nf*16+rsel)*32 + ko];
    #pragma unroll
    for (int mf=0;mf<4;mf++)
      #pragma unroll
      for (int nf=0;nf<4;nf++)
        acc[mf][nf] = __builtin_amdgcn_mfma_f32_16x16x32_bf16(af[mf], bfr[nf], acc[mf][nf], 0,0,0);
  }
  int crow = bm+wm+(l>>4)*4;
  int ccol = bn+wn+(l&15);
  #pragma unroll
  for (int mf=0;mf<4;mf++)
    #pragma unroll
    for (int nf=0;nf<4;nf++)
      #pragma unroll
      for (int r2=0;r2<4;r2++)
        cstore(C, (size_t)(crow+mf*16+r2)*N + ccol+nf*16, acc[mf][nf][r2]);
}

// ---------------- rotary (theta_shift) in-place on q and k; k gets DK^-0.5 ----------------
__global__ __launch_bounds__(256) void rotary_kernel(ushort* __restrict__ q, ushort* __restrict__ k,
                                                     const float* __restrict__ sint,
                                                     const float* __restrict__ cost) {
  int idx = blockIdx.x*256+threadIdx.x;   // over 16000*512 pairs
  if (idx >= 16000*512) return;
  int row = idx>>9, cp = idx&511;
  int col = cp*2;
  int t = row - (row/4000)*4000;
  int d = col & 127;
  float c = cost[(size_t)t*128+d], s = sint[(size_t)t*128+d];
  uint* qp = (uint*)(q + (size_t)row*1024 + col);
  uint w = *qp;
  float q0=bflo(w), q1=bfhi(w);
  *qp = pack2(q0*c - q1*s, q1*c + q0*s);
  uint* kp = (uint*)(k + (size_t)row*1024 + col);
  w = *kp;
  float k0=bflo(w), k1=bfhi(w);
  const float sc = 0.08838834764831845f;  // 128^-0.5
  *kp = pack2((k0*c - k1*s)*sc, (k1*c + k0*s)*sc);
}

// ---------------- kv[bnh][128][128] = kr^T @ (v * value_inner_decay) ----------------
__global__ __launch_bounds__(256) void kv_kernel(const ushort* __restrict__ kr,
                                                 const ushort* __restrict__ v,
                                                 float* __restrict__ kv) {
  int bnh = blockIdx.x;
  int h = bnh&7, n=(bnh>>3)&7, b=bnh>>6;
  size_t base = (size_t)(b*4000+n*500)*1024 + h*128;
  float Dh = 1.0f - exp2f(-5.0f-(float)h);
  float decay = logf(Dh);
  float ls = (1.0f - expf(decay*500.0f))/(1.0f-Dh);
  float inv_ls = 1.0f/ls;
  __shared__ ushort krt[64][128];
  __shared__ ushort vdt[64][128];
  int tid=threadIdx.x;
  int tk=tid>>4, tv=tid&15;
  int srow=tid>>2, sc0=(tid&3)*32;
  float acc[8][8];
  #pragma unroll
  for (int i=0;i<8;i++)
    #pragma unroll
    for(int j=0;j<8;j++) acc[i][j]=0;
  for (int ct=0; ct<500; ct+=64) {
    int cn = min(64, 500-ct);
    __syncthreads();
    if (srow<cn) {
      const ushort* kp = kr + base + (size_t)(ct+srow)*1024 + sc0;
      const ushort* vp = v  + base + (size_t)(ct+srow)*1024 + sc0;
      float vid = expf(decay*(float)(499-(ct+srow)))*inv_ls;
      #pragma unroll
      for (int j=0;j<4;j++) {
        *(uint4*)&krt[srow][sc0+j*8] = *(const uint4*)(kp+j*8);
        uint4 vv = *(const uint4*)(vp+j*8);
        float vf[8]; unpack8(vv,vf);
        uint4 w2;
        w2.x = pack2(vf[0]*vid, vf[1]*vid);
        w2.y = pack2(vf[2]*vid, vf[3]*vid);
        w2.z = pack2(vf[4]*vid, vf[5]*vid);
        w2.w = pack2(vf[6]*vid, vf[7]*vid);
        *(uint4*)&vdt[srow][sc0+j*8] = w2;
      }
    }
    __syncthreads();
    for (int c=0;c<cn;c++) {
      uint4 ka = *(const uint4*)&krt[c][tk*8];
      uint4 vb = *(const uint4*)&vdt[c][tv*8];
      float kf[8], vf[8];
      unpack8(ka,kf); unpack8(vb,vf);
      #pragma unroll
      for (int i=0;i<8;i++)
        #pragma unroll
        for (int j=0;j<8;j++)
          acc[i][j] += kf[i]*vf[j];
    }
  }
  float* outp = kv + (size_t)bnh*16384;
  #pragma unroll
  for (int i=0;i<8;i++)
    #pragma unroll
    for (int j=0;j<8;j++)
      outp[(size_t)(tk*8+i)*128 + tv*8+j] = acc[i][j];
}

// ------- sequential scan over chunks per (b,h); kvrec emitted bf16 TRANSPOSED [dv][k] -------
__global__ __launch_bounds__(256) void scan_kernel(const float* __restrict__ kv,
                                                   ushort* __restrict__ kvrecT,
                                                   float* __restrict__ crosssc) {
  int bh = blockIdx.x;           // 32
  int b = bh>>3, h = bh&7;
  float Dh = 1.0f - exp2f(-5.0f-(float)h);
  float decay = logf(Dh);
  float cd = expf(decay*500.0f); // cross_decay
  int tid=threadIdx.x;
  int vcol = tid&127, khalf = tid>>7;
  float st[64];
  #pragma unroll
  for (int i=0;i<64;i++) st[i]=0;
  float scale = 1.0f;
  __shared__ float colpart[2][128];
  __shared__ float sred[2];
  for (int n=0;n<8;n++) {
    int bnh = (b*8+n)*8+h;
    const float* src = kv + (size_t)bnh*16384;
    ushort* rec = kvrecT + (size_t)bnh*16384;
    float inv = 1.0f/scale;
    float cs = 0;
    #pragma unroll
    for (int i=0;i<64;i++) {
      int kk = khalf*64+i;
      rec[(size_t)vcol*128+kk] = f2bf(st[i]*inv);   // transposed: [dv][k]
      st[i] = st[i]*cd + src[(size_t)kk*128+vcol];
      cs += fabsf(st[i]);
    }
    if (tid==0) crosssc[bnh] = scale;
    colpart[khalf][vcol] = cs;
    __syncthreads();
    if (tid<128) colpart[0][tid] += colpart[1][tid];
    __syncthreads();
    float m = (tid<128)? colpart[0][tid] : 0.0f;
    #pragma unroll
    for (int o=32;o;o>>=1) m = fmaxf(m,__shfl_xor(m,o));
    if (tid<128 && (tid&63)==0) sred[tid>>6]=m;
    __syncthreads();
    scale = fmaxf(fmaxf(sred[0],sred[1]),1.0f);
    __syncthreads();
  }
}

// ---- MFMA retention: S=QK^T (masked, abs-rowsum) ; O_inner=P@V ; O_cross=Q@kvrec ; combine ----
__global__ __launch_bounds__(256) void iout_mfma(const ushort* __restrict__ qr,
                                                 const ushort* __restrict__ kr,
                                                 const ushort* __restrict__ v,
                                                 const ushort* __restrict__ kvrecT,
                                                 const float* __restrict__ crosssc,
                                                 ushort* __restrict__ O) {
  int bnh = blockIdx.x, rt = blockIdx.y;
  int h = bnh&7, n=(bnh>>3)&7, b=bnh>>6;
  size_t base = (size_t)(b*4000+n*500)*1024 + h*128;
  float Dh = 1.0f - exp2f(-5.0f-(float)h);
  float decay = logf(Dh);

  __shared__ ushort sh[31232];       // 62464 B
  ushort* qt = sh;                   // [64][136]  Q rows
  ushort* kt = sh + 8704;            // [64][136]  K rows (e-tile)
  ushort* vt = sh + 17408;           // [128][72]  V^T (e-tile)
  ushort* pt = sh + 26624;           // [64][72]   P tile
  ushort* kvt = sh + 8704;           // phase2: [128][136] kvrec^T (reuses kt+vt)

  int tid = threadIdx.x;
  int wv = tid>>6, l = tid&63;
  int g = l>>4, c16 = l&15;
  int srow = tid>>2, sc0 = (tid&3)*32;

  {
    int gq = rt*64+srow; if (gq>499) gq=499;
    const ushort* src = qr + base + (size_t)gq*1024 + sc0;
    #pragma unroll
    for (int j=0;j<4;j++) *(uint4*)&qt[srow*136 + sc0 + j*8] = *(const uint4*)(src + j*8);
  }
  int r_base = rt*64 + wv*16 + g*4;
  float er[4];
  #pragma unroll
  for (int reg=0;reg<4;reg++) er[reg] = expf(decay*(float)(r_base+reg));

  f32x4 pv[8], cc[8];
  #pragma unroll
  for (int i=0;i<8;i++){
    #pragma unroll
    for (int j=0;j<4;j++){ pv[i][j]=0.0f; cc[i][j]=0.0f; }
  }
  float rowsum[4] = {0,0,0,0};
  __syncthreads();

  for (int et=0; et<=rt; et++) {
    if (et) __syncthreads();
    {
      int ge = et*64+srow; if (ge>499) ge=499;
      const ushort* ks = kr + base + (size_t)ge*1024 + sc0;
      const ushort* vs = v  + base + (size_t)ge*1024 + sc0;
      #pragma unroll
      for (int j=0;j<4;j++) {
        *(uint4*)&kt[srow*136 + sc0 + j*8] = *(const uint4*)(ks + j*8);
        union{uint4 u; ushort s[8];} tv; tv.u = *(const uint4*)(vs + j*8);
        #pragma unroll
        for (int x=0;x<8;x++) vt[(sc0+j*8+x)*72 + srow] = tv.s[x];
      }
    }
    __syncthreads();
    f32x4 S[4];
    #pragma unroll
    for (int i=0;i<4;i++){ S[i][0]=0; S[i][1]=0; S[i][2]=0; S[i][3]=0; }
    #pragma unroll
    for (int kc=0;kc<4;kc++) {
      s16x8 a = *(const s16x8*)&qt[(wv*16 + c16)*136 + kc*32 + g*8];
      #pragma unroll
      for (int ni=0;ni<4;ni++) {
        s16x8 bf2 = *(const s16x8*)&kt[(ni*16 + c16)*136 + kc*32 + g*8];
        S[ni] = __builtin_amdgcn_mfma_f32_16x16x32_bf16(a, bf2, S[ni], 0,0,0);
      }
    }
    #pragma unroll
    for (int ni=0;ni<4;ni++) {
      int e_rel = et*64 + ni*16 + c16;
      float ie = expf(-decay*(float)e_rel);
      #pragma unroll
      for (int reg=0;reg<4;reg++) {
        int rr = r_base + reg;
        float p = (e_rel <= rr) ? S[ni][reg]*er[reg]*ie : 0.0f;
        rowsum[reg] += fabsf(p);
        pt[(wv*16 + g*4 + reg)*72 + ni*16 + c16] = f2bf(p);
      }
    }
    #pragma unroll
    for (int kc=0;kc<2;kc++) {
      s16x8 pa = *(const s16x8*)&pt[(wv*16 + c16)*72 + kc*32 + g*8];
      #pragma unroll
      for (int nf=0;nf<8;nf++) {
        s16x8 vb = *(const s16x8*)&vt[(nf*16 + c16)*72 + kc*32 + g*8];
        pv[nf] = __builtin_amdgcn_mfma_f32_16x16x32_bf16(pa, vb, pv[nf], 0,0,0);
      }
    }
  }
  #pragma unroll
  for (int reg=0;reg<4;reg++) {
    float s = rowsum[reg];
    s += __shfl_xor(s,1); s += __shfl_xor(s,2); s += __shfl_xor(s,4); s += __shfl_xor(s,8);
    rowsum[reg] = s;
  }
  __syncthreads();
  {
    int r2 = tid>>1, c0 = (tid&1)*64;
    const ushort* src = kvrecT + (size_t)bnh*16384 + (size_t)r2*128 + c0;
    #pragma unroll
    for (int j=0;j<8;j++) *(uint4*)&kvt[r2*136 + c0 + j*8] = *(const uint4*)(src + j*8);
  }
  __syncthreads();
  #pragma unroll
  for (int kc=0;kc<4;kc++) {
    s16x8 a = *(const s16x8*)&qt[(wv*16 + c16)*136 + kc*32 + g*8];
    #pragma unroll
    for (int nf=0;nf<8;nf++) {
      s16x8 bb = *(const s16x8*)&kvt[(nf*16 + c16)*136 + kc*32 + g*8];
      cc[nf] = __builtin_amdgcn_mfma_f32_16x16x32_bf16(a, bb, cc[nf], 0,0,0);
    }
  }
  float cs = crosssc[bnh];
  float lsum = (1.0f-expf(decay*500.0f))/(1.0f-Dh);
  #pragma unroll
  for (int reg=0;reg<4;reg++) {
    int rr = r_base + reg;
    if (rr < 500) {
      float rs = (1.0f-expf(decay*(float)(rr+1)))/(1.0f-Dh);
      float rsr = rsqrtf(rs);
      float is = fmaxf(1.0f, rowsum[reg]*rsr);
      float all = fmaxf(is, cs);
      float qid = expf(decay*(float)(rr+1))*lsum*rsr;
      float fi = rsr/all;
      float fc = qid*(cs/all);
      ushort* dst = O + (size_t)(b*4000+n*500+rr)*1024 + h*128;
      #pragma unroll
      for (int nf=0;nf<8;nf++)
        dst[nf*16 + c16] = f2bf(pv[nf][reg]*fi + cc[nf][reg]*fc);
    }
  }
}

// ---------------- per-head RMS norm + silu(g) gate ----------------
__global__ __launch_bounds__(256) void rms_silu_kernel(const ushort* __restrict__ O,
                                                       const ushort* __restrict__ g,
                                                       ushort* __restrict__ op) {
  int row = blockIdx.x, tid=threadIdx.x;
  int wave=tid>>6, lane=tid&63;
  const ushort* Orow = O + (size_t)row*1024;
  const ushort* grow = g + (size_t)row*1024;
  ushort* orow = op + (size_t)row*1024;
  for (int hh=0; hh<2; hh++) {
    int h = wave*2+hh;
    int c0 = h*128+lane, c1=c0+64;
    float a = bfu(Orow[c0]), b2 = bfu(Orow[c1]);
    float ss = a*a+b2*b2;
    #pragma unroll
    for (int o=32;o;o>>=1) ss += __shfl_xor(ss,o);
    float sc = rsqrtf(ss*(1.0f/128.0f)+1e-6f);
    float g0=bfu(grow[c0]), g1=bfu(grow[c1]);
    float s0 = g0/(1.0f+expf(-g0)), s1 = g1/(1.0f+expf(-g1));
    orow[c0] = f2bf(s0*a*sc);
    orow[c1] = f2bf(s1*b2*sc);
  }
}

extern "C" void kernel_launch(void* const* d_in, const int* in_sizes, int n_in,
                              void* d_out, int out_size, void* d_ws, size_t ws_size,
                              hipStream_t stream) {
  const float* x     = (const float*)d_in[0];
  const float* gamma = (const float*)d_in[1];
  const float* beta  = (const float*)d_in[2];
  const float* Wq    = (const float*)d_in[3];
  const float* Wk    = (const float*)d_in[4];
  const float* Wv    = (const float*)d_in[5];
  const float* Wg    = (const float*)d_in[6];
  const float* Wo    = (const float*)d_in[7];
  float* out = (float*)d_out;

  char* ws = (char*)d_ws;
  size_t off = 0;
  auto alloc = [&](size_t bytes)->void* { void* p = ws+off; off += (bytes+255)&~(size_t)255; return p; };
  const size_t BT1024 = (size_t)16000*1024;
  ushort* xln  = (ushort*)alloc(BT1024*2);   // reused as opre after g-GEMM
  ushort* q    = (ushort*)alloc(BT1024*2);
  ushort* k    = (ushort*)alloc(BT1024*2);
  ushort* v    = (ushort*)alloc(BT1024*2);
  ushort* g    = (ushort*)alloc(BT1024*2);
  ushort* O    = (ushort*)alloc(BT1024*2);
  ushort* WqT  = (ushort*)alloc((size_t)1024*1024*2);
  ushort* WkT  = (ushort*)alloc((size_t)1024*1024*2);
  ushort* WvT  = (ushort*)alloc((size_t)1024*1024*2);
  ushort* WgT  = (ushort*)alloc((size_t)1024*1024*2);
  ushort* WoT  = (ushort*)alloc((size_t)1024*1024*2);
  float* sint  = (float*)alloc((size_t)4000*128*4);
  float* cost  = (float*)alloc((size_t)4000*128*4);
  float* kv    = (float*)alloc((size_t)256*16384*4);
  ushort* kvrecT=(ushort*)alloc((size_t)256*16384*2);
  float* crosssc = (float*)alloc(256*4);
  (void)ws_size; (void)in_sizes; (void)n_in; (void)out_size;

  ln_kernel<<<16000,256,0,stream>>>(x,gamma,beta,xln);
  sincos_kernel<<<1000,256,0,stream>>>(sint,cost);
  dim3 tt(16,16);
  f2bf_t_kernel<<<tt,256,0,stream>>>(Wq,WqT);
  f2bf_t_kernel<<<tt,256,0,stream>>>(Wk,WkT);
  f2bf_t_kernel<<<tt,256,0,stream>>>(Wv,WvT);
  f2bf_t_kernel<<<tt,256,0,stream>>>(Wg,WgT);
  f2bf_t_kernel<<<tt,256,0,stream>>>(Wo,WoT);

  dim3 gg(125,8);
  gemm_bt<ushort><<<gg,256,0,stream>>>(xln,WqT,q,16000,1024,1024);
  gemm_bt<ushort><<<gg,256,0,stream>>>(xln,WkT,k,16000,1024,1024);
  gemm_bt<ushort><<<gg,256,0,stream>>>(xln,WvT,v,16000,1024,1024);
  gemm_bt<ushort><<<gg,256,0,stream>>>(xln,WgT,g,16000,1024,1024);

  rotary_kernel<<<32000,256,0,stream>>>(q,k,sint,cost);

  kv_kernel<<<256,256,0,stream>>>(k,v,kv);
  scan_kernel<<<32,256,0,stream>>>(kv,kvrecT,crosssc);

  dim3 gr(256,8);
  iout_mfma<<<gr,256,0,stream>>>(q,k,v,kvrecT,crosssc,O);

  ushort* opre = xln;   // xln dead after the 4 projection GEMMs
  rms_silu_kernel<<<16000,256,0,stream>>>(O,g,opre);
  gemm_bt<float><<<gg,256,0,stream>>>(opre,WoT,out,16000,1024,1024);
}

// Round 5
// 471.354 us; speedup vs baseline: 2.6638x; 1.2091x over previous
//
#include <hip/hip_runtime.h>
#include <hip/hip_bf16.h>

// B=4, T=4000, D=1024, H=8, DK=128, CHUNK=500, N=T/CHUNK=8
// I/O is fp32 (per reference); internal activations bf16, accumulation fp32.

typedef __attribute__((ext_vector_type(4))) float f32x4;
typedef __attribute__((ext_vector_type(8))) short s16x8;

#define DEV static __device__ __forceinline__

DEV float bfu(ushort u){ union{uint i; float f;} x; x.i=((uint)u)<<16; return x.f; }
DEV float bflo(uint w){ union{uint i; float f;} x; x.i=w<<16; return x.f; }
DEV float bfhi(uint w){ union{uint i; float f;} x; x.i=w&0xffff0000u; return x.f; }
DEV ushort f2bf(float f){ union{float f; uint u;} x; x.f=f; uint r = x.u + 0x7fffu + ((x.u>>16)&1u); return (ushort)(r>>16); }
DEV uint pack2(float lo, float hi){ return ((uint)f2bf(hi)<<16) | (uint)f2bf(lo); }
DEV void unpack8(uint4 u, float* f){
  f[0]=bflo(u.x); f[1]=bfhi(u.x); f[2]=bflo(u.y); f[3]=bfhi(u.y);
  f[4]=bflo(u.z); f[5]=bfhi(u.z); f[6]=bflo(u.w); f[7]=bfhi(u.w);
}
DEV void cstore(float* C, size_t i, float v){ C[i]=v; }
DEV void cstore(ushort* C, size_t i, float v){ C[i]=f2bf(v); }

// async global->LDS, 16B per lane; lds dest = wave-uniform base + lane*16
DEV void gload16(const ushort* g, ushort* l) {
  __builtin_amdgcn_global_load_lds((const __attribute__((address_space(1))) void*)g,
                                   (__attribute__((address_space(3))) void*)l, 16, 0, 0);
}

// ---------------- fp32 W[K][N] -> bf16 W^T[N][K] (64x64 tile transpose) ----------------
__global__ __launch_bounds__(256) void f2bf_t_kernel(const float* __restrict__ src,
                                                     ushort* __restrict__ dst) {
  __shared__ ushort t[64][72];
  int kt = blockIdx.x*64, nt = blockIdx.y*64;
  int tid = threadIdx.x;
  int r = tid>>2, c0 = (tid&3)*16;
  const float* s = src + (size_t)(kt+r)*1024 + nt + c0;
  #pragma unroll
  for (int j=0;j<16;j+=4) {
    float4 vv = *(const float4*)(s+j);
    t[r][c0+j]=f2bf(vv.x); t[r][c0+j+1]=f2bf(vv.y); t[r][c0+j+2]=f2bf(vv.z); t[r][c0+j+3]=f2bf(vv.w);
  }
  __syncthreads();
  union { uint4 u4[2]; ushort s16[16]; } tmp;
  #pragma unroll
  for (int j=0;j<16;j++) tmp.s16[j] = t[c0+j][r];
  ushort* d = dst + (size_t)(nt+r)*1024 + kt + c0;
  *(uint4*)(d)   = tmp.u4[0];
  *(uint4*)(d+8) = tmp.u4[1];
}

// ---------------- LayerNorm: fp32 in, bf16 out; one block per row of 1024 ----------------
__global__ __launch_bounds__(256) void ln_kernel(const float* __restrict__ x,
                                                 const float* __restrict__ gamma,
                                                 const float* __restrict__ beta,
                                                 ushort* __restrict__ xo) {
  int row = blockIdx.x;
  int tid = threadIdx.x;
  const float* xr = x + (size_t)row*1024;
  float4 u = ((const float4*)xr)[tid];
  float s = u.x+u.y+u.z+u.w;
  float sq = u.x*u.x+u.y*u.y+u.z*u.z+u.w*u.w;
  #pragma unroll
  for (int o=32;o;o>>=1){ s += __shfl_xor(s,o); sq += __shfl_xor(sq,o); }
  __shared__ float red[8];
  int wv=tid>>6, ln=tid&63;
  if (ln==0){ red[wv]=s; red[4+wv]=sq; }
  __syncthreads();
  s = red[0]+red[1]+red[2]+red[3];
  sq = red[4]+red[5]+red[6]+red[7];
  float mu = s*(1.0f/1024.0f);
  float var = sq*(1.0f/1024.0f)-mu*mu;
  float inv = rsqrtf(var+1e-5f);
  float4 gg = ((const float4*)gamma)[tid];
  float4 bb = ((const float4*)beta)[tid];
  float o0=(u.x-mu)*inv*gg.x+bb.x;
  float o1=(u.y-mu)*inv*gg.y+bb.y;
  float o2=(u.z-mu)*inv*gg.z+bb.z;
  float o3=(u.w-mu)*inv*gg.w+bb.w;
  uint2 w; w.x=pack2(o0,o1); w.y=pack2(o2,o3);
  ((uint2*)(xo+(size_t)row*1024))[tid]=w;
}

// ---------------- sin/cos tables: [4000][128] fp32 ----------------
__global__ __launch_bounds__(256) void sincos_kernel(float* __restrict__ sint, float* __restrict__ cost) {
  int idx = blockIdx.x*256+threadIdx.x;
  if (idx >= 4000*64) return;
  int t = idx>>6, i = idx&63;
  float ang = expf(-9.210340371976184f * (float)i * (1.0f/63.0f)); // 10000^(-i/63)
  float a = (float)t * ang;
  float sv = sinf(a), cv = cosf(a);
  sint[(size_t)t*128+2*i] = sv; sint[(size_t)t*128+2*i+1] = sv;
  cost[(size_t)t*128+2*i] = cv; cost[(size_t)t*128+2*i+1] = cv;
}

// ---------------- MFMA bf16 GEMM (B^T form): C[M,N] = A[M,K] @ BT[N,K]^T ----------------
// 128x128 tile, BK=32, 4 waves, global_load_lds width=16 staging, XCD-aware swizzle.
template<typename OutT>
__global__ __launch_bounds__(256) void gemm_bt(const ushort* __restrict__ A,
                                               const ushort* __restrict__ BT,
                                               OutT* __restrict__ C,
                                               int M, int N, int K) {
  __shared__ ushort As[128*32];
  __shared__ ushort Bs[128*32];
  // XCD swizzle: nwg = (M/128)*(N/128), N/128 assumed 8, nwg%8==0.
  int ny = N>>7;
  int cpx = ((M>>7)*ny)>>3;
  int wg = blockIdx.x;
  int orig = (wg&7)*cpx + (wg>>3);    // each XCD gets a contiguous x-major chunk
  int bm = (orig>>3)*128, bn = (orig&7)*128;
  int tid = threadIdx.x;
  int w = tid>>6, l = tid&63;
  int wm = (w>>1)*64, wn = (w&1)*64;
  int rsel = l&15, ko = (l>>4)*8;
  f32x4 acc[4][4];
  #pragma unroll
  for (int i=0;i<4;i++)
    #pragma unroll
    for (int j=0;j<4;j++){ acc[i][j][0]=0; acc[i][j][1]=0; acc[i][j][2]=0; acc[i][j][3]=0; }
  const ushort* ap0 = A  + (size_t)(bm + w*32 + (l>>2))*K + (l&3)*8;
  const ushort* ap1 = ap0 + (size_t)16*K;
  const ushort* bp0 = BT + (size_t)(bn + w*32 + (l>>2))*K + (l&3)*8;
  const ushort* bp1 = bp0 + (size_t)16*K;
  ushort* abase = As + w*1024;
  ushort* bbase = Bs + w*1024;
  for (int kt=0; kt<K; kt+=32) {
    __syncthreads();
    gload16(ap0+kt, abase);
    gload16(ap1+kt, abase+512);
    gload16(bp0+kt, bbase);
    gload16(bp1+kt, bbase+512);
    __syncthreads();
    s16x8 af[4], bfr[4];
    #pragma unroll
    for (int mf=0;mf<4;mf++) af[mf]  = *(const s16x8*)&As[(wm+mf*16+rsel)*32 + ko];
    #pragma unroll
    for (int nf=0;nf<4;nf++) bfr[nf] = *(const s16x8*)&Bs[(wn+nf*16+rsel)*32 + ko];
    #pragma unroll
    for (int mf=0;mf<4;mf++)
      #pragma unroll
      for (int nf=0;nf<4;nf++)
        acc[mf][nf] = __builtin_amdgcn_mfma_f32_16x16x32_bf16(af[mf], bfr[nf], acc[mf][nf], 0,0,0);
  }
  int crow = bm+wm+(l>>4)*4;
  int ccol = bn+wn+(l&15);
  #pragma unroll
  for (int mf=0;mf<4;mf++)
    #pragma unroll
    for (int nf=0;nf<4;nf++)
      #pragma unroll
      for (int r2=0;r2<4;r2++)
        cstore(C, (size_t)(crow+mf*16+r2)*N + ccol+nf*16, acc[mf][nf][r2]);
}

// ---------------- rotary (theta_shift) in-place on q and k; k gets DK^-0.5 ----------------
__global__ __launch_bounds__(256) void rotary_kernel(ushort* __restrict__ q, ushort* __restrict__ k,
                                                     const float* __restrict__ sint,
                                                     const float* __restrict__ cost) {
  int idx = blockIdx.x*256+threadIdx.x;   // over 16000*512 pairs
  if (idx >= 16000*512) return;
  int row = idx>>9, cp = idx&511;
  int col = cp*2;
  int t = row - (row/4000)*4000;
  int d = col & 127;
  float c = cost[(size_t)t*128+d], s = sint[(size_t)t*128+d];
  uint* qp = (uint*)(q + (size_t)row*1024 + col);
  uint w = *qp;
  float q0=bflo(w), q1=bfhi(w);
  *qp = pack2(q0*c - q1*s, q1*c + q0*s);
  uint* kp = (uint*)(k + (size_t)row*1024 + col);
  w = *kp;
  float k0=bflo(w), k1=bfhi(w);
  const float sc = 0.08838834764831845f;  // 128^-0.5
  *kp = pack2((k0*c - k1*s)*sc, (k1*c + k0*s)*sc);
}

// ---- MFMA kv: kvp[half][bnh][dk][dv] = sum_c k[c][dk] * v[c][dv]*vid(c)  (c-split in 2) ----
__global__ __launch_bounds__(256) void kv_mfma(const ushort* __restrict__ kr,
                                               const ushort* __restrict__ v,
                                               float* __restrict__ kvp) {
  int bnh = blockIdx.x, half = blockIdx.y;
  int h = bnh&7, n=(bnh>>3)&7, b=bnh>>6;
  size_t base = (size_t)(b*4000+n*500)*1024 + h*128;
  float Dh = 1.0f - exp2f(-5.0f-(float)h);
  float decay = logf(Dh);
  float ls = (1.0f - expf(decay*500.0f))/(1.0f-Dh);
  float inv_ls = 1.0f/ls;
  __shared__ ushort kT[128*72];   // [dk][c] (c stride 1, row stride 72)
  __shared__ ushort vT[128*72];   // [dv][c], pre-scaled by vid
  int tid=threadIdx.x;
  int wv=tid>>6, l=tid&63, g=l>>4, c16=l&15;
  int srow=tid>>2, sc0=(tid&3)*32;
  int cbeg = half*250, cend = cbeg+250;
  f32x4 acc[2][8];
  #pragma unroll
  for (int i=0;i<2;i++)
    #pragma unroll
    for (int j=0;j<8;j++){ acc[i][j][0]=0; acc[i][j][1]=0; acc[i][j][2]=0; acc[i][j][3]=0; }
  for (int ct=cbeg; ct<cend; ct+=64) {
    if (ct!=cbeg) __syncthreads();
    int c = ct + srow;
    int cc = min(c, 499);
    const ushort* ks = kr + base + (size_t)cc*1024 + sc0;
    const ushort* vs = v  + base + (size_t)cc*1024 + sc0;
    float vid = (c < cend && c < 500) ? expf(decay*(float)(499-c))*inv_ls : 0.0f;
    #pragma unroll
    for (int j=0;j<4;j++) {
      union{uint4 u; ushort s[8];} tk; tk.u = *(const uint4*)(ks+j*8);
      uint4 vv = *(const uint4*)(vs+j*8);
      float vf[8]; unpack8(vv,vf);
      #pragma unroll
      for (int x=0;x<8;x++) {
        kT[(sc0+j*8+x)*72 + srow] = tk.s[x];
        vT[(sc0+j*8+x)*72 + srow] = f2bf(vf[x]*vid);
      }
    }
    __syncthreads();
    #pragma unroll
    for (int kc=0;kc<2;kc++) {
      s16x8 a0 = *(const s16x8*)&kT[(wv*32 +      c16)*72 + kc*32 + g*8];
      s16x8 a1 = *(const s16x8*)&kT[(wv*32 + 16 + c16)*72 + kc*32 + g*8];
      #pragma unroll
      for (int nf=0;nf<8;nf++) {
        s16x8 bb = *(const s16x8*)&vT[(nf*16 + c16)*72 + kc*32 + g*8];
        acc[0][nf] = __builtin_amdgcn_mfma_f32_16x16x32_bf16(a0, bb, acc[0][nf], 0,0,0);
        acc[1][nf] = __builtin_amdgcn_mfma_f32_16x16x32_bf16(a1, bb, acc[1][nf], 0,0,0);
      }
    }
  }
  float* outp = kvp + ((size_t)half*256 + bnh)*16384;
  #pragma unroll
  for (int mf=0;mf<2;mf++)
    #pragma unroll
    for (int nf=0;nf<8;nf++)
      #pragma unroll
      for (int reg=0;reg<4;reg++)
        outp[(size_t)(wv*32 + mf*16 + g*4 + reg)*128 + nf*16 + c16] = acc[mf][nf][reg];
}

// ------- sequential scan over chunks per (b,h); kvrec emitted bf16 TRANSPOSED [dv][k] -------
__global__ __launch_bounds__(256) void scan_kernel(const float* __restrict__ kvp,
                                                   ushort* __restrict__ kvrecT,
                                                   float* __restrict__ crosssc) {
  int bh = blockIdx.x;           // 32
  int b = bh>>3, h = bh&7;
  float Dh = 1.0f - exp2f(-5.0f-(float)h);
  float decay = logf(Dh);
  float cd = expf(decay*500.0f); // cross_decay
  int tid=threadIdx.x;
  int vcol = tid&127, khalf = tid>>7;
  float st[64];
  #pragma unroll
  for (int i=0;i<64;i++) st[i]=0;
  float scale = 1.0f;
  __shared__ float colpart[2][128];
  __shared__ float sred[2];
  for (int n=0;n<8;n++) {
    int bnh = (b*8+n)*8+h;
    const float* s0 = kvp + (size_t)bnh*16384;
    const float* s1 = kvp + (size_t)(256+bnh)*16384;
    ushort* rec = kvrecT + (size_t)bnh*16384;
    float inv = 1.0f/scale;
    float cs = 0;
    #pragma unroll
    for (int i=0;i<64;i++) {
      int kk = khalf*64+i;
      rec[(size_t)vcol*128+kk] = f2bf(st[i]*inv);   // transposed: [dv][k]
      st[i] = st[i]*cd + s0[(size_t)kk*128+vcol] + s1[(size_t)kk*128+vcol];
      cs += fabsf(st[i]);
    }
    if (tid==0) crosssc[bnh] = scale;
    colpart[khalf][vcol] = cs;
    __syncthreads();
    if (tid<128) colpart[0][tid] += colpart[1][tid];
    __syncthreads();
    float m = (tid<128)? colpart[0][tid] : 0.0f;
    #pragma unroll
    for (int o=32;o;o>>=1) m = fmaxf(m,__shfl_xor(m,o));
    if (tid<128 && (tid&63)==0) sred[tid>>6]=m;
    __syncthreads();
    scale = fmaxf(fmaxf(sred[0],sred[1]),1.0f);
    __syncthreads();
  }
}

// ---- MFMA retention: S=QK^T (masked, abs-rowsum) ; O_inner=P@V ; O_cross=Q@kvrec ; combine ----
__global__ __launch_bounds__(256) void iout_mfma(const ushort* __restrict__ qr,
                                                 const ushort* __restrict__ kr,
                                                 const ushort* __restrict__ v,
                                                 const ushort* __restrict__ kvrecT,
                                                 const float* __restrict__ crosssc,
                                                 ushort* __restrict__ O) {
  int bnh = blockIdx.x, rt = blockIdx.y;
  int h = bnh&7, n=(bnh>>3)&7, b=bnh>>6;
  size_t base = (size_t)(b*4000+n*500)*1024 + h*128;
  float Dh = 1.0f - exp2f(-5.0f-(float)h);
  float decay = logf(Dh);

  __shared__ ushort sh[31232];       // 62464 B
  ushort* qt = sh;                   // [64][136]  Q rows
  ushort* kt = sh + 8704;            // [64][136]  K rows (e-tile)
  ushort* vt = sh + 17408;           // [128][72]  V^T (e-tile)
  ushort* pt = sh + 26624;           // [64][72]   P tile
  ushort* kvt = sh + 8704;           // phase2: [128][136] kvrec^T (reuses kt+vt)

  int tid = threadIdx.x;
  int wv = tid>>6, l = tid&63;
  int g = l>>4, c16 = l&15;
  int srow = tid>>2, sc0 = (tid&3)*32;

  {
    int gq = rt*64+srow; if (gq>499) gq=499;
    const ushort* src = qr + base + (size_t)gq*1024 + sc0;
    #pragma unroll
    for (int j=0;j<4;j++) *(uint4*)&qt[srow*136 + sc0 + j*8] = *(const uint4*)(src + j*8);
  }
  int r_base = rt*64 + wv*16 + g*4;
  float er[4];
  #pragma unroll
  for (int reg=0;reg<4;reg++) er[reg] = expf(decay*(float)(r_base+reg));

  f32x4 pv[8], cc[8];
  #pragma unroll
  for (int i=0;i<8;i++){
    #pragma unroll
    for (int j=0;j<4;j++){ pv[i][j]=0.0f; cc[i][j]=0.0f; }
  }
  float rowsum[4] = {0,0,0,0};
  __syncthreads();

  for (int et=0; et<=rt; et++) {
    if (et) __syncthreads();
    {
      int ge = et*64+srow; if (ge>499) ge=499;
      const ushort* ks = kr + base + (size_t)ge*1024 + sc0;
      const ushort* vs = v  + base + (size_t)ge*1024 + sc0;
      #pragma unroll
      for (int j=0;j<4;j++) {
        *(uint4*)&kt[srow*136 + sc0 + j*8] = *(const uint4*)(ks + j*8);
        union{uint4 u; ushort s[8];} tv; tv.u = *(const uint4*)(vs + j*8);
        #pragma unroll
        for (int x=0;x<8;x++) vt[(sc0+j*8+x)*72 + srow] = tv.s[x];
      }
    }
    __syncthreads();
    f32x4 S[4];
    #pragma unroll
    for (int i=0;i<4;i++){ S[i][0]=0; S[i][1]=0; S[i][2]=0; S[i][3]=0; }
    #pragma unroll
    for (int kc=0;kc<4;kc++) {
      s16x8 a = *(const s16x8*)&qt[(wv*16 + c16)*136 + kc*32 + g*8];
      #pragma unroll
      for (int ni=0;ni<4;ni++) {
        s16x8 bf2 = *(const s16x8*)&kt[(ni*16 + c16)*136 + kc*32 + g*8];
        S[ni] = __builtin_amdgcn_mfma_f32_16x16x32_bf16(a, bf2, S[ni], 0,0,0);
      }
    }
    #pragma unroll
    for (int ni=0;ni<4;ni++) {
      int e_rel = et*64 + ni*16 + c16;
      float ie = expf(-decay*(float)e_rel);
      #pragma unroll
      for (int reg=0;reg<4;reg++) {
        int rr = r_base + reg;
        float p = (e_rel <= rr) ? S[ni][reg]*er[reg]*ie : 0.0f;
        rowsum[reg] += fabsf(p);
        pt[(wv*16 + g*4 + reg)*72 + ni*16 + c16] = f2bf(p);
      }
    }
    #pragma unroll
    for (int kc=0;kc<2;kc++) {
      s16x8 pa = *(const s16x8*)&pt[(wv*16 + c16)*72 + kc*32 + g*8];
      #pragma unroll
      for (int nf=0;nf<8;nf++) {
        s16x8 vb = *(const s16x8*)&vt[(nf*16 + c16)*72 + kc*32 + g*8];
        pv[nf] = __builtin_amdgcn_mfma_f32_16x16x32_bf16(pa, vb, pv[nf], 0,0,0);
      }
    }
  }
  #pragma unroll
  for (int reg=0;reg<4;reg++) {
    float s = rowsum[reg];
    s += __shfl_xor(s,1); s += __shfl_xor(s,2); s += __shfl_xor(s,4); s += __shfl_xor(s,8);
    rowsum[reg] = s;
  }
  __syncthreads();
  {
    int r2 = tid>>1, c0 = (tid&1)*64;
    const ushort* src = kvrecT + (size_t)bnh*16384 + (size_t)r2*128 + c0;
    #pragma unroll
    for (int j=0;j<8;j++) *(uint4*)&kvt[r2*136 + c0 + j*8] = *(const uint4*)(src + j*8);
  }
  __syncthreads();
  #pragma unroll
  for (int kc=0;kc<4;kc++) {
    s16x8 a = *(const s16x8*)&qt[(wv*16 + c16)*136 + kc*32 + g*8];
    #pragma unroll
    for (int nf=0;nf<8;nf++) {
      s16x8 bb = *(const s16x8*)&kvt[(nf*16 + c16)*136 + kc*32 + g*8];
      cc[nf] = __builtin_amdgcn_mfma_f32_16x16x32_bf16(a, bb, cc[nf], 0,0,0);
    }
  }
  float cs = crosssc[bnh];
  float lsum = (1.0f-expf(decay*500.0f))/(1.0f-Dh);
  #pragma unroll
  for (int reg=0;reg<4;reg++) {
    int rr = r_base + reg;
    if (rr < 500) {
      float rs = (1.0f-expf(decay*(float)(rr+1)))/(1.0f-Dh);
      float rsr = rsqrtf(rs);
      float is = fmaxf(1.0f, rowsum[reg]*rsr);
      float all = fmaxf(is, cs);
      float qid = expf(decay*(float)(rr+1))*lsum*rsr;
      float fi = rsr/all;
      float fc = qid*(cs/all);
      ushort* dst = O + (size_t)(b*4000+n*500+rr)*1024 + h*128;
      #pragma unroll
      for (int nf=0;nf<8;nf++)
        dst[nf*16 + c16] = f2bf(pv[nf][reg]*fi + cc[nf][reg]*fc);
    }
  }
}

// ---------------- per-head RMS norm + silu(g) gate ----------------
__global__ __launch_bounds__(256) void rms_silu_kernel(const ushort* __restrict__ O,
                                                       const ushort* __restrict__ g,
                                                       ushort* __restrict__ op) {
  int row = blockIdx.x, tid=threadIdx.x;
  int wave=tid>>6, lane=tid&63;
  const ushort* Orow = O + (size_t)row*1024;
  const ushort* grow = g + (size_t)row*1024;
  ushort* orow = op + (size_t)row*1024;
  for (int hh=0; hh<2; hh++) {
    int h = wave*2+hh;
    int c0 = h*128+lane, c1=c0+64;
    float a = bfu(Orow[c0]), b2 = bfu(Orow[c1]);
    float ss = a*a+b2*b2;
    #pragma unroll
    for (int o=32;o;o>>=1) ss += __shfl_xor(ss,o);
    float sc = rsqrtf(ss*(1.0f/128.0f)+1e-6f);
    float g0=bfu(grow[c0]), g1=bfu(grow[c1]);
    float s0 = g0/(1.0f+expf(-g0)), s1 = g1/(1.0f+expf(-g1));
    orow[c0] = f2bf(s0*a*sc);
    orow[c1] = f2bf(s1*b2*sc);
  }
}

extern "C" void kernel_launch(void* const* d_in, const int* in_sizes, int n_in,
                              void* d_out, int out_size, void* d_ws, size_t ws_size,
                              hipStream_t stream) {
  const float* x     = (const float*)d_in[0];
  const float* gamma = (const float*)d_in[1];
  const float* beta  = (const float*)d_in[2];
  const float* Wq    = (const float*)d_in[3];
  const float* Wk    = (const float*)d_in[4];
  const float* Wv    = (const float*)d_in[5];
  const float* Wg    = (const float*)d_in[6];
  const float* Wo    = (const float*)d_in[7];
  float* out = (float*)d_out;

  char* ws = (char*)d_ws;
  size_t off = 0;
  auto alloc = [&](size_t bytes)->void* { void* p = ws+off; off += (bytes+255)&~(size_t)255; return p; };
  const size_t BT1024 = (size_t)16000*1024;
  ushort* xln  = (ushort*)alloc(BT1024*2);   // reused as opre after g-GEMM
  ushort* q    = (ushort*)alloc(BT1024*2);
  ushort* k    = (ushort*)alloc(BT1024*2);
  ushort* v    = (ushort*)alloc(BT1024*2);
  ushort* g    = (ushort*)alloc(BT1024*2);
  ushort* O    = (ushort*)alloc(BT1024*2);
  ushort* WqT  = (ushort*)alloc((size_t)1024*1024*2);
  ushort* WkT  = (ushort*)alloc((size_t)1024*1024*2);
  ushort* WvT  = (ushort*)alloc((size_t)1024*1024*2);
  ushort* WgT  = (ushort*)alloc((size_t)1024*1024*2);
  ushort* WoT  = (ushort*)alloc((size_t)1024*1024*2);
  float* sint  = (float*)alloc((size_t)4000*128*4);
  float* cost  = (float*)alloc((size_t)4000*128*4);
  float* kvp   = (float*)alloc((size_t)512*16384*4);   // 2 c-halves of partial kv
  ushort* kvrecT=(ushort*)alloc((size_t)256*16384*2);
  float* crosssc = (float*)alloc(256*4);
  (void)ws_size; (void)in_sizes; (void)n_in; (void)out_size;

  ln_kernel<<<16000,256,0,stream>>>(x,gamma,beta,xln);
  sincos_kernel<<<1000,256,0,stream>>>(sint,cost);
  dim3 tt(16,16);
  f2bf_t_kernel<<<tt,256,0,stream>>>(Wq,WqT);
  f2bf_t_kernel<<<tt,256,0,stream>>>(Wk,WkT);
  f2bf_t_kernel<<<tt,256,0,stream>>>(Wv,WvT);
  f2bf_t_kernel<<<tt,256,0,stream>>>(Wg,WgT);
  f2bf_t_kernel<<<tt,256,0,stream>>>(Wo,WoT);

  gemm_bt<ushort><<<1000,256,0,stream>>>(xln,WqT,q,16000,1024,1024);
  gemm_bt<ushort><<<1000,256,0,stream>>>(xln,WkT,k,16000,1024,1024);
  gemm_bt<ushort><<<1000,256,0,stream>>>(xln,WvT,v,16000,1024,1024);
  gemm_bt<ushort><<<1000,256,0,stream>>>(xln,WgT,g,16000,1024,1024);

  rotary_kernel<<<32000,256,0,stream>>>(q,k,sint,cost);

  dim3 gkv(256,2);
  kv_mfma<<<gkv,256,0,stream>>>(k,v,kvp);
  scan_kernel<<<32,256,0,stream>>>(kvp,kvrecT,crosssc);

  dim3 gr(256,8);
  iout_mfma<<<gr,256,0,stream>>>(q,k,v,kvrecT,crosssc,O);

  ushort* opre = xln;   // xln dead after the 4 projection GEMMs
  rms_silu_kernel<<<16000,256,0,stream>>>(O,g,opre);
  gemm_bt<float><<<1000,256,0,stream>>>(opre,WoT,out,16000,1024,1024);
}